// Round 2
// baseline (45629.919 us; speedup 1.0000x reference)
//
#include <hip/hip_runtime.h>
#include <stdint.h>

#define NSIZE   64
#define NPTS    8192
#define NTILE   64
#define NBLOCKS 8192

struct Keys { uint32_t k0[5]; uint32_t k1[5]; };

// ---------------- threefry2x32, 20 rounds (JAX-compatible) ----------------
#define TF_ROUNDS_A(x0,x1) \
  x0 += x1; x1 = (x1<<13)|(x1>>19); x1 ^= x0; \
  x0 += x1; x1 = (x1<<15)|(x1>>17); x1 ^= x0; \
  x0 += x1; x1 = (x1<<26)|(x1>>6);  x1 ^= x0; \
  x0 += x1; x1 = (x1<<6) |(x1>>26); x1 ^= x0;
#define TF_ROUNDS_B(x0,x1) \
  x0 += x1; x1 = (x1<<17)|(x1>>15); x1 ^= x0; \
  x0 += x1; x1 = (x1<<29)|(x1>>3);  x1 ^= x0; \
  x0 += x1; x1 = (x1<<16)|(x1>>16); x1 ^= x0; \
  x0 += x1; x1 = (x1<<24)|(x1>>8);  x1 ^= x0;

__host__ __device__ inline void threefry2x32(uint32_t k0, uint32_t k1,
                                             uint32_t c0, uint32_t c1,
                                             uint32_t& o0, uint32_t& o1) {
  uint32_t k2 = k0 ^ k1 ^ 0x1BD11BDAu;
  uint32_t x0 = c0 + k0, x1 = c1 + k1;
  TF_ROUNDS_A(x0,x1) x0 += k1; x1 += k2 + 1u;
  TF_ROUNDS_B(x0,x1) x0 += k2; x1 += k0 + 2u;
  TF_ROUNDS_A(x0,x1) x0 += k0; x1 += k1 + 3u;
  TF_ROUNDS_B(x0,x1) x0 += k1; x1 += k2 + 4u;
  TF_ROUNDS_A(x0,x1) x0 += k2; x1 += k0 + 5u;
  o0 = x0; o1 = x1;
}

// JAX partitionable random_bits + jax.random.normal (Giles erfinv), verified r1.
__device__ __forceinline__ float jax_normal32(uint32_t k0, uint32_t k1, uint32_t idx) {
  uint32_t o0, o1;
  threefry2x32(k0, k1, 0u, idx, o0, o1);
  uint32_t bits = o0 ^ o1;
  float u01 = __uint_as_float((bits >> 9) | 0x3f800000u) - 1.0f;
  float u = __fadd_rn(__fmul_rn(u01, 2.0f), -0.99999994f);
  u = fmaxf(u, -0.99999994f);
  float xx = __fmul_rn(u, u);
  float w = -log1pf(-xx);
  float p;
  if (w < 5.0f) {
    w = __fadd_rn(w, -2.5f);
    p =                2.81022636e-08f;
    p = __fadd_rn( 3.43273939e-07f, __fmul_rn(p, w));
    p = __fadd_rn(-3.5233877e-06f,  __fmul_rn(p, w));
    p = __fadd_rn(-4.39150654e-06f, __fmul_rn(p, w));
    p = __fadd_rn( 0.00021858087f,  __fmul_rn(p, w));
    p = __fadd_rn(-0.00125372503f,  __fmul_rn(p, w));
    p = __fadd_rn(-0.00417768164f,  __fmul_rn(p, w));
    p = __fadd_rn( 0.246640727f,    __fmul_rn(p, w));
    p = __fadd_rn( 1.50140941f,     __fmul_rn(p, w));
  } else {
    w = __fadd_rn(__fsqrt_rn(w), -3.0f);
    p =               -0.000200214257f;
    p = __fadd_rn( 0.000100950558f, __fmul_rn(p, w));
    p = __fadd_rn( 0.00134934322f,  __fmul_rn(p, w));
    p = __fadd_rn(-0.00367342844f,  __fmul_rn(p, w));
    p = __fadd_rn( 0.00573950773f,  __fmul_rn(p, w));
    p = __fadd_rn(-0.0076224613f,   __fmul_rn(p, w));
    p = __fadd_rn( 0.00943887047f,  __fmul_rn(p, w));
    p = __fadd_rn( 1.00167406f,     __fmul_rn(p, w));
    p = __fadd_rn( 2.83297682f,     __fmul_rn(p, w));
  }
  return __fmul_rn(1.41421356f, __fmul_rn(p, u));
}

__device__ __forceinline__ float softplus_ref(float x) {
  float l = log1pf(expf(fminf(x, 20.0f)));
  return (x > 20.0f) ? x : l;
}

// 512 threads, one (s, 64-row tile) per block, SINGLE column pass (no zh carry).
__global__ __launch_bounds__(512, 4)
void vsiren_kernel(const float* __restrict__ X,
                   const float* __restrict__ mu0, const float* __restrict__ ls0,
                   const float* __restrict__ mu1, const float* __restrict__ ls1,
                   const float* __restrict__ mu2, const float* __restrict__ ls2,
                   const float* __restrict__ mu3, const float* __restrict__ ls3,
                   const float* __restrict__ mu4, const float* __restrict__ ls4,
                   float* __restrict__ out, Keys keys)
{
  __shared__ float hT[256][64];     // 64 KB: hT[feature][row]
  __shared__ float s2b[16][256];    // 16 KB: softplus(ls)^2, 16 k-rows x 256 cols

  const int tid = threadIdx.x;
  const uint32_t bid = blockIdx.x;
  const uint32_t swz = (bid & 7u) * 1024u + (bid >> 3);   // XCD swizzle
  const int s  = (int)(swz >> 7);
  const int n0 = (int)(swz & 127u) * NTILE;

  float* sX = &s2b[0][0];
  if (tid < 2 * NTILE) sX[tid] = X[(size_t)(s * NPTS + n0) * 2 + tid];
  __syncthreads();

  // ---- posenc ----
  {
    const int r = tid & 63, p = tid >> 6;           // p: {d, trig, khalf}
    const int d = p & 1, trg = (p >> 1) & 1, kh = p >> 2;
    const float xv = sX[r * 2 + d];
    const float delta = 6.93147182464599609375f / 63.0f;
    #pragma unroll 8
    for (int k = 0; k < 32; ++k) {
      const int kf = kh * 32 + k;
      float w = expf(__fmul_rn((float)kf, delta));
      float arg = __fmul_rn(3.14159274101257324f, __fmul_rn(xv, w));
      hT[trg * 128 + d * 64 + kf][r] = trg ? sinf(arg) : cosf(arg);
    }
  }
  // (chunk-0 barrier below orders posenc reads/writes vs s2b restage)

  const int tc = tid & 31;          // col group: cols tc*8..tc*8+7
  const int tr = tid >> 5;          // row group: rows tr*4..tr*4+3  (also k-row for staging)
  // XOR chunk swizzle for s2b: logical 16B-chunk c stored at c ^ ((c>>3)&7)
  const int c0 = 2 * tc, c1 = 2 * tc + 1;
  const int o0 = (c0 ^ ((c0 >> 3) & 7)) * 4;   // float offset within a 256-float row
  const int o1 = (c1 ^ ((c1 >> 3) & 7)) * 4;
  const float* s2f = &s2b[0][0];

  for (int l = 0; l < 4; ++l) {
    const float* __restrict__ mu =
        ((l == 0) ? mu0 : (l == 1) ? mu1 : (l == 2) ? mu2 : mu3) + (size_t)s * (257 * 256);
    const float* __restrict__ ls =
        ((l == 0) ? ls0 : (l == 1) ? ls1 : (l == 2) ? ls2 : ls3) + (size_t)s * (257 * 256);
    const uint32_t lk0 = (l == 0) ? keys.k0[0] : (l == 1) ? keys.k0[1] : (l == 2) ? keys.k0[2] : keys.k0[3];
    const uint32_t lk1 = (l == 0) ? keys.k1[0] : (l == 1) ? keys.k1[1] : (l == 2) ? keys.k1[2] : keys.k1[3];

    float am[4][8], av[4][8];
    #pragma unroll
    for (int i = 0; i < 4; ++i)
      #pragma unroll
      for (int j = 0; j < 8; ++j) { am[i][j] = 0.f; av[i][j] = 0.f; }

    #pragma unroll 1
    for (int ch = 0; ch < 16; ++ch) {
      __syncthreads();             // previous chunk's s2b reads (or posenc) done
      {
        const float* lsrow = ls + (size_t)(ch * 16 + tr) * 256 + tc * 8;
        const float4 l0v = *(const float4*)lsrow;
        const float4 l1v = *(const float4*)(lsrow + 4);
        float a0 = softplus_ref(l0v.x), a1 = softplus_ref(l0v.y);
        float a2 = softplus_ref(l0v.z), a3 = softplus_ref(l0v.w);
        float b0 = softplus_ref(l1v.x), b1 = softplus_ref(l1v.y);
        float b2 = softplus_ref(l1v.z), b3 = softplus_ref(l1v.w);
        float* dst = &s2b[tr][0];
        *(float4*)(dst + o0) = make_float4(__fmul_rn(a0, a0), __fmul_rn(a1, a1),
                                           __fmul_rn(a2, a2), __fmul_rn(a3, a3));
        *(float4*)(dst + o1) = make_float4(__fmul_rn(b0, b0), __fmul_rn(b1, b1),
                                           __fmul_rn(b2, b2), __fmul_rn(b3, b3));
      }
      __syncthreads();             // staged chunk visible (also first-iter: hT ready)

      const float* abase = &hT[ch * 16][tr * 4];
      const float* wbase = mu + (size_t)(ch * 16) * 256 + tc * 8;

      #pragma unroll
      for (int kk = 0; kk < 16; ++kk) {
        const float4 a  = *(const float4*)(abase + kk * 64);
        const float4 w0 = *(const float4*)(wbase + kk * 256);
        const float4 w1 = *(const float4*)(wbase + kk * 256 + 4);
        const float4 q0 = *(const float4*)(s2f + kk * 256 + o0);
        const float4 q1 = *(const float4*)(s2f + kk * 256 + o1);
        const float ar[4] = {a.x, a.y, a.z, a.w};
        const float wm[8] = {w0.x, w0.y, w0.z, w0.w, w1.x, w1.y, w1.z, w1.w};
        const float ws[8] = {q0.x, q0.y, q0.z, q0.w, q1.x, q1.y, q1.z, q1.w};
        #pragma unroll
        for (int rr = 0; rr < 4; ++rr) {
          const float hv = ar[rr];
          const float h2 = __fmul_rn(hv, hv);
          #pragma unroll
          for (int c = 0; c < 8; ++c) {
            am[rr][c] = fmaf(hv, wm[c], am[rr][c]);
            av[rr][c] = fmaf(h2, ws[c], av[rr][c]);
          }
        }
      }
    }

    // ---- epilogue: bias, variance, noise, sin — results overwrite am ----
    {
      const float* mub_p = mu + 256 * 256;
      const float* lsb_p = ls + 256 * 256;
      #pragma unroll
      for (int c = 0; c < 8; ++c) {
        const int col = tc * 8 + c;
        const float mub = mub_p[col];
        const float spb = softplus_ref(lsb_p[col]);
        const float vb  = __fmul_rn(spb, spb);
        #pragma unroll
        for (int rr = 0; rr < 4; ++rr) {
          float m   = __fadd_rn(am[rr][c], mub);
          float var = __fadd_rn(__fadd_rn(av[rr][c], vb), 1e-14f);
          float sv  = __fsqrt_rn(var);
          uint32_t idx = ((uint32_t)(s * NPTS + n0 + tr * 4 + rr)) * 256u + (uint32_t)col;
          float nz = jax_normal32(lk0, lk1, idx);
          float z  = __fadd_rn(m, __fmul_rn(sv, nz));
          am[rr][c] = sinf(__fmul_rn(30.0f, z));
        }
      }
    }
    __syncthreads();               // all hT reads for this layer done
    #pragma unroll
    for (int c = 0; c < 8; ++c) {
      *(float4*)&hT[tc * 8 + c][tr * 4] =
          make_float4(am[0][c], am[1][c], am[2][c], am[3][c]);
    }
    __syncthreads();
  } // layer

  // ---- layer 4: 256 -> 3, last=True (no sin) ----
  {
    const float* __restrict__ mu = mu4 + (size_t)s * (257 * 3);
    const float* __restrict__ ls = ls4 + (size_t)s * (257 * 3);
    float* s2w = &s2b[0][0];
    for (int e = tid; e < 771; e += 512) {
      float sp = softplus_ref(ls[e]);
      s2w[e] = __fmul_rn(sp, sp);
    }
    __syncthreads();

    const int r = tid >> 3, o = tid & 7;
    if (o < 3) {
      float am = 0.f, av2 = 0.f;
      #pragma unroll 4
      for (int k = 0; k < 256; ++k) {
        float hv = hT[k][r];
        am  = fmaf(hv, mu[k * 3 + o], am);
        av2 = fmaf(__fmul_rn(hv, hv), s2w[k * 3 + o], av2);
      }
      float m   = __fadd_rn(am, mu[256 * 3 + o]);
      float var = __fadd_rn(__fadd_rn(av2, s2w[256 * 3 + o]), 1e-14f);
      float sv  = __fsqrt_rn(var);
      const int n = n0 + r;
      uint32_t idx = ((uint32_t)(s * NPTS + n)) * 3u + (uint32_t)o;
      float nz = jax_normal32(keys.k0[4], keys.k1[4], idx);
      out[(size_t)(s * NPTS + n) * 3 + o] = __fadd_rn(m, __fmul_rn(sv, nz));
    }
  }
}

extern "C" void kernel_launch(void* const* d_in, const int* in_sizes, int n_in,
                              void* d_out, int out_size, void* d_ws, size_t ws_size,
                              hipStream_t stream) {
  (void)in_sizes; (void)n_in; (void)d_ws; (void)ws_size; (void)out_size;
  const float* X   = (const float*)d_in[0];
  const float* mu0 = (const float*)d_in[1];
  const float* ls0 = (const float*)d_in[2];
  const float* mu1 = (const float*)d_in[3];
  const float* ls1 = (const float*)d_in[4];
  const float* mu2 = (const float*)d_in[5];
  const float* ls2 = (const float*)d_in[6];
  const float* mu3 = (const float*)d_in[7];
  const float* ls3 = (const float*)d_in[8];
  const float* mu4 = (const float*)d_in[9];
  const float* ls4 = (const float*)d_in[10];

  Keys keys;
  for (int l = 0; l < 5; ++l) {
    uint32_t o0, o1;
    threefry2x32(0u, 42u, 0u, (uint32_t)l, o0, o1);
    keys.k0[l] = o0; keys.k1[l] = o1;
  }

  vsiren_kernel<<<dim3(NBLOCKS), dim3(512), 0, stream>>>(
      X, mu0, ls0, mu1, ls1, mu2, ls2, mu3, ls3, mu4, ls4,
      (float*)d_out, keys);
}

// Round 3
// 19788.263 us; speedup vs baseline: 2.3059x; 2.3059x over previous
//
#include <hip/hip_runtime.h>
#include <stdint.h>

#define NSIZE   64
#define NPTS    8192
#define NTILE   64
#define NBLOCKS 8192

struct Keys { uint32_t k0[5]; uint32_t k1[5]; };

// ---------------- threefry2x32, 20 rounds (JAX-compatible) ----------------
#define TF_ROUNDS_A(x0,x1) \
  x0 += x1; x1 = (x1<<13)|(x1>>19); x1 ^= x0; \
  x0 += x1; x1 = (x1<<15)|(x1>>17); x1 ^= x0; \
  x0 += x1; x1 = (x1<<26)|(x1>>6);  x1 ^= x0; \
  x0 += x1; x1 = (x1<<6) |(x1>>26); x1 ^= x0;
#define TF_ROUNDS_B(x0,x1) \
  x0 += x1; x1 = (x1<<17)|(x1>>15); x1 ^= x0; \
  x0 += x1; x1 = (x1<<29)|(x1>>3);  x1 ^= x0; \
  x0 += x1; x1 = (x1<<16)|(x1>>16); x1 ^= x0; \
  x0 += x1; x1 = (x1<<24)|(x1>>8);  x1 ^= x0;

__host__ __device__ inline void threefry2x32(uint32_t k0, uint32_t k1,
                                             uint32_t c0, uint32_t c1,
                                             uint32_t& o0, uint32_t& o1) {
  uint32_t k2 = k0 ^ k1 ^ 0x1BD11BDAu;
  uint32_t x0 = c0 + k0, x1 = c1 + k1;
  TF_ROUNDS_A(x0,x1) x0 += k1; x1 += k2 + 1u;
  TF_ROUNDS_B(x0,x1) x0 += k2; x1 += k0 + 2u;
  TF_ROUNDS_A(x0,x1) x0 += k0; x1 += k1 + 3u;
  TF_ROUNDS_B(x0,x1) x0 += k1; x1 += k2 + 4u;
  TF_ROUNDS_A(x0,x1) x0 += k2; x1 += k0 + 5u;
  o0 = x0; o1 = x1;
}

// JAX partitionable random_bits + jax.random.normal (Giles erfinv), verified r1.
__device__ __forceinline__ float jax_normal32(uint32_t k0, uint32_t k1, uint32_t idx) {
  uint32_t o0, o1;
  threefry2x32(k0, k1, 0u, idx, o0, o1);
  uint32_t bits = o0 ^ o1;
  float u01 = __uint_as_float((bits >> 9) | 0x3f800000u) - 1.0f;
  float u = __fadd_rn(__fmul_rn(u01, 2.0f), -0.99999994f);
  u = fmaxf(u, -0.99999994f);
  float xx = __fmul_rn(u, u);
  float w = -log1pf(-xx);
  float p;
  if (w < 5.0f) {
    w = __fadd_rn(w, -2.5f);
    p =                2.81022636e-08f;
    p = __fadd_rn( 3.43273939e-07f, __fmul_rn(p, w));
    p = __fadd_rn(-3.5233877e-06f,  __fmul_rn(p, w));
    p = __fadd_rn(-4.39150654e-06f, __fmul_rn(p, w));
    p = __fadd_rn( 0.00021858087f,  __fmul_rn(p, w));
    p = __fadd_rn(-0.00125372503f,  __fmul_rn(p, w));
    p = __fadd_rn(-0.00417768164f,  __fmul_rn(p, w));
    p = __fadd_rn( 0.246640727f,    __fmul_rn(p, w));
    p = __fadd_rn( 1.50140941f,     __fmul_rn(p, w));
  } else {
    w = __fadd_rn(__fsqrt_rn(w), -3.0f);
    p =               -0.000200214257f;
    p = __fadd_rn( 0.000100950558f, __fmul_rn(p, w));
    p = __fadd_rn( 0.00134934322f,  __fmul_rn(p, w));
    p = __fadd_rn(-0.00367342844f,  __fmul_rn(p, w));
    p = __fadd_rn( 0.00573950773f,  __fmul_rn(p, w));
    p = __fadd_rn(-0.0076224613f,   __fmul_rn(p, w));
    p = __fadd_rn( 0.00943887047f,  __fmul_rn(p, w));
    p = __fadd_rn( 1.00167406f,     __fmul_rn(p, w));
    p = __fadd_rn( 2.83297682f,     __fmul_rn(p, w));
  }
  return __fmul_rn(1.41421356f, __fmul_rn(p, u));
}

__device__ __forceinline__ float softplus_ref(float x) {
  float l = log1pf(expf(fminf(x, 20.0f)));
  return (x > 20.0f) ? x : l;
}

// hT row swizzle: kills the transposed-write bank conflict.
// row' = row ^ (((col>>3)&15)<<2)  — bijective, 4-aligned blocks preserved.
#define HT_IDX(col, row) (((col) << 6) + ((row) ^ ((((col) >> 3) & 15) << 2)))

// 512 threads, one (s, 64-row tile) per block, single column pass.
// launch_bounds(512,2): on this toolchain 2nd arg acts like min-BLOCKS/CU
// (r2 evidence: arg=4 -> VGPR cap 64 -> catastrophic spill). 2 -> cap 128.
__global__ __launch_bounds__(512, 2)
void vsiren_kernel(const float* __restrict__ X,
                   const float* __restrict__ mu0, const float* __restrict__ ls0,
                   const float* __restrict__ mu1, const float* __restrict__ ls1,
                   const float* __restrict__ mu2, const float* __restrict__ ls2,
                   const float* __restrict__ mu3, const float* __restrict__ ls3,
                   const float* __restrict__ mu4, const float* __restrict__ ls4,
                   float* __restrict__ out, Keys keys)
{
  __shared__ float hTf[256 * 64];   // 64 KB, swizzled via HT_IDX
  __shared__ float s2b[16][256];    // 16 KB: softplus(ls)^2 chunk

  const int tid = threadIdx.x;
  const uint32_t bid = blockIdx.x;
  const uint32_t swz = (bid & 7u) * 1024u + (bid >> 3);   // XCD swizzle
  const int s  = (int)(swz >> 7);
  const int n0 = (int)(swz & 127u) * NTILE;

  float* sX = &s2b[0][0];
  if (tid < 2 * NTILE) sX[tid] = X[(size_t)(s * NPTS + n0) * 2 + tid];
  __syncthreads();

  // ---- posenc ----
  {
    const int r = tid & 63, p = tid >> 6;
    const int d = p & 1, trg = (p >> 1) & 1, kh = p >> 2;
    const float xv = sX[r * 2 + d];
    const float delta = 6.93147182464599609375f / 63.0f;
    #pragma unroll 8
    for (int k = 0; k < 32; ++k) {
      const int kf = kh * 32 + k;
      const int f = trg * 128 + d * 64 + kf;
      float w = expf(__fmul_rn((float)kf, delta));
      float arg = __fmul_rn(3.14159274101257324f, __fmul_rn(xv, w));
      hTf[HT_IDX(f, r)] = trg ? sinf(arg) : cosf(arg);
    }
  }
  // first chunk barrier below orders posenc writes vs matmul reads

  const int tc = tid & 31;          // col group: cols tc*8..tc*8+7
  const int tr = tid >> 5;          // row group: rows tr*4..tr*4+3
  // XOR chunk swizzle for s2b rows (16B-chunk c stored at c ^ ((c>>3)&7))
  const int c0 = 2 * tc, c1 = 2 * tc + 1;
  const int o0 = (c0 ^ ((c0 >> 3) & 7)) * 4;
  const int o1 = (c1 ^ ((c1 >> 3) & 7)) * 4;
  const float* s2f = &s2b[0][0];

  for (int l = 0; l < 4; ++l) {
    const float* __restrict__ mu =
        ((l == 0) ? mu0 : (l == 1) ? mu1 : (l == 2) ? mu2 : mu3) + (size_t)s * (257 * 256);
    const float* __restrict__ ls =
        ((l == 0) ? ls0 : (l == 1) ? ls1 : (l == 2) ? ls2 : ls3) + (size_t)s * (257 * 256);
    const uint32_t lk0 = (l == 0) ? keys.k0[0] : (l == 1) ? keys.k0[1] : (l == 2) ? keys.k0[2] : keys.k0[3];
    const uint32_t lk1 = (l == 0) ? keys.k1[0] : (l == 1) ? keys.k1[1] : (l == 2) ? keys.k1[2] : keys.k1[3];

    float am[4][8], av[4][8];
    #pragma unroll
    for (int i = 0; i < 4; ++i)
      #pragma unroll
      for (int j = 0; j < 8; ++j) { am[i][j] = 0.f; av[i][j] = 0.f; }

    #pragma unroll 1
    for (int ch = 0; ch < 16; ++ch) {
      __syncthreads();             // previous chunk's s2b reads (or posenc) done
      {
        const float* lsrow = ls + (size_t)(ch * 16 + tr) * 256 + tc * 8;
        const float4 l0v = *(const float4*)lsrow;
        const float4 l1v = *(const float4*)(lsrow + 4);
        float a0 = softplus_ref(l0v.x), a1 = softplus_ref(l0v.y);
        float a2 = softplus_ref(l0v.z), a3 = softplus_ref(l0v.w);
        float b0 = softplus_ref(l1v.x), b1 = softplus_ref(l1v.y);
        float b2 = softplus_ref(l1v.z), b3 = softplus_ref(l1v.w);
        float* dst = &s2b[tr][0];
        *(float4*)(dst + o0) = make_float4(__fmul_rn(a0, a0), __fmul_rn(a1, a1),
                                           __fmul_rn(a2, a2), __fmul_rn(a3, a3));
        *(float4*)(dst + o1) = make_float4(__fmul_rn(b0, b0), __fmul_rn(b1, b1),
                                           __fmul_rn(b2, b2), __fmul_rn(b3, b3));
      }
      __syncthreads();             // staged chunk visible (first iter: hT ready too)

      const int rowA = tr * 4;
      const int xk0 = ((ch * 2) & 15) << 2;
      const int xk1 = ((ch * 2 + 1) & 15) << 2;
      const float* abase0 = &hTf[((ch * 16    ) << 6) + (rowA ^ xk0)];
      const float* abase1 = &hTf[((ch * 16 + 8) << 6) + (rowA ^ xk1)];
      const float* wbase = mu + (size_t)(ch * 16) * 256 + tc * 8;

      #pragma unroll
      for (int kk = 0; kk < 16; ++kk) {
        const float4 a = (kk < 8) ? *(const float4*)(abase0 + kk * 64)
                                  : *(const float4*)(abase1 + (kk - 8) * 64);
        const float4 w0 = *(const float4*)(wbase + kk * 256);
        const float4 w1 = *(const float4*)(wbase + kk * 256 + 4);
        const float4 q0 = *(const float4*)(s2f + kk * 256 + o0);
        const float4 q1 = *(const float4*)(s2f + kk * 256 + o1);
        const float ar[4] = {a.x, a.y, a.z, a.w};
        const float wm[8] = {w0.x, w0.y, w0.z, w0.w, w1.x, w1.y, w1.z, w1.w};
        const float ws[8] = {q0.x, q0.y, q0.z, q0.w, q1.x, q1.y, q1.z, q1.w};
        #pragma unroll
        for (int rr = 0; rr < 4; ++rr) {
          const float hv = ar[rr];
          const float h2 = __fmul_rn(hv, hv);
          #pragma unroll
          for (int c = 0; c < 8; ++c) {
            am[rr][c] = fmaf(hv, wm[c], am[rr][c]);
            av[rr][c] = fmaf(h2, ws[c], av[rr][c]);
          }
        }
      }
    }

    // ---- epilogue: bias, variance, noise, sin — results overwrite am ----
    {
      const float* mub_p = mu + 256 * 256;
      const float* lsb_p = ls + 256 * 256;
      #pragma unroll
      for (int c = 0; c < 8; ++c) {
        const int col = tc * 8 + c;
        const float mub = mub_p[col];
        const float spb = softplus_ref(lsb_p[col]);
        const float vb  = __fmul_rn(spb, spb);
        #pragma unroll
        for (int rr = 0; rr < 4; ++rr) {
          float m   = __fadd_rn(am[rr][c], mub);
          float var = __fadd_rn(__fadd_rn(av[rr][c], vb), 1e-14f);
          float sv  = __fsqrt_rn(var);
          uint32_t idx = ((uint32_t)(s * NPTS + n0 + tr * 4 + rr)) * 256u + (uint32_t)col;
          float nz = jax_normal32(lk0, lk1, idx);
          float z  = __fadd_rn(m, __fmul_rn(sv, nz));
          am[rr][c] = sinf(__fmul_rn(30.0f, z));
        }
      }
    }
    __syncthreads();               // all hT reads for this layer done
    {
      const int wrow = (tr * 4) ^ ((tc & 15) << 2);   // col>>3 == tc for c<8
      #pragma unroll
      for (int c = 0; c < 8; ++c) {
        *(float4*)&hTf[((tc * 8 + c) << 6) + wrow] =
            make_float4(am[0][c], am[1][c], am[2][c], am[3][c]);
      }
    }
    __syncthreads();
  } // layer

  // ---- layer 4: 256 -> 3, last=True (no sin) ----
  {
    const float* __restrict__ mu = mu4 + (size_t)s * (257 * 3);
    const float* __restrict__ ls = ls4 + (size_t)s * (257 * 3);
    float* s2w = &s2b[0][0];
    for (int e = tid; e < 771; e += 512) {
      float sp = softplus_ref(ls[e]);
      s2w[e] = __fmul_rn(sp, sp);
    }
    __syncthreads();

    const int r = tid >> 3, o = tid & 7;
    if (o < 3) {
      float am = 0.f, av2 = 0.f;
      #pragma unroll 4
      for (int k = 0; k < 256; ++k) {
        float hv = hTf[HT_IDX(k, r)];
        am  = fmaf(hv, mu[k * 3 + o], am);
        av2 = fmaf(__fmul_rn(hv, hv), s2w[k * 3 + o], av2);
      }
      float m   = __fadd_rn(am, mu[256 * 3 + o]);
      float var = __fadd_rn(__fadd_rn(av2, s2w[256 * 3 + o]), 1e-14f);
      float sv  = __fsqrt_rn(var);
      const int n = n0 + r;
      uint32_t idx = ((uint32_t)(s * NPTS + n)) * 3u + (uint32_t)o;
      float nz = jax_normal32(keys.k0[4], keys.k1[4], idx);
      out[(size_t)(s * NPTS + n) * 3 + o] = __fadd_rn(m, __fmul_rn(sv, nz));
    }
  }
}

extern "C" void kernel_launch(void* const* d_in, const int* in_sizes, int n_in,
                              void* d_out, int out_size, void* d_ws, size_t ws_size,
                              hipStream_t stream) {
  (void)in_sizes; (void)n_in; (void)d_ws; (void)ws_size; (void)out_size;
  const float* X   = (const float*)d_in[0];
  const float* mu0 = (const float*)d_in[1];
  const float* ls0 = (const float*)d_in[2];
  const float* mu1 = (const float*)d_in[3];
  const float* ls1 = (const float*)d_in[4];
  const float* mu2 = (const float*)d_in[5];
  const float* ls2 = (const float*)d_in[6];
  const float* mu3 = (const float*)d_in[7];
  const float* ls3 = (const float*)d_in[8];
  const float* mu4 = (const float*)d_in[9];
  const float* ls4 = (const float*)d_in[10];

  Keys keys;
  for (int l = 0; l < 5; ++l) {
    uint32_t o0, o1;
    threefry2x32(0u, 42u, 0u, (uint32_t)l, o0, o1);
    keys.k0[l] = o0; keys.k1[l] = o1;
  }

  vsiren_kernel<<<dim3(NBLOCKS), dim3(512), 0, stream>>>(
      X, mu0, ls0, mu1, ls1, mu2, ls2, mu3, ls3, mu4, ls4,
      (float*)d_out, keys);
}

// Round 4
// 16487.268 us; speedup vs baseline: 2.7676x; 1.2002x over previous
//
#include <hip/hip_runtime.h>
#include <stdint.h>

#define NSIZE   64
#define NPTS    8192
#define NTILE   16
#define NBLOCKS (NSIZE * (NPTS / NTILE))   // 32768

// ws layout (floats): 4 big layers of 64*257*256, then layer4 64*257*3
#define WS_L    4210688                    // 64*257*256
#define WS_L4   16842752                   // 4*WS_L
#define WS_TOT  16892096                   // + 64*771
#define WS_BYTES ((size_t)WS_TOT * 4)

struct Keys { uint32_t k0[5]; uint32_t k1[5]; };

// ---------------- threefry2x32, 20 rounds (JAX-compatible) ----------------
#define TF_ROUNDS_A(x0,x1) \
  x0 += x1; x1 = (x1<<13)|(x1>>19); x1 ^= x0; \
  x0 += x1; x1 = (x1<<15)|(x1>>17); x1 ^= x0; \
  x0 += x1; x1 = (x1<<26)|(x1>>6);  x1 ^= x0; \
  x0 += x1; x1 = (x1<<6) |(x1>>26); x1 ^= x0;
#define TF_ROUNDS_B(x0,x1) \
  x0 += x1; x1 = (x1<<17)|(x1>>15); x1 ^= x0; \
  x0 += x1; x1 = (x1<<29)|(x1>>3);  x1 ^= x0; \
  x0 += x1; x1 = (x1<<16)|(x1>>16); x1 ^= x0; \
  x0 += x1; x1 = (x1<<24)|(x1>>8);  x1 ^= x0;

__host__ __device__ inline void threefry2x32(uint32_t k0, uint32_t k1,
                                             uint32_t c0, uint32_t c1,
                                             uint32_t& o0, uint32_t& o1) {
  uint32_t k2 = k0 ^ k1 ^ 0x1BD11BDAu;
  uint32_t x0 = c0 + k0, x1 = c1 + k1;
  TF_ROUNDS_A(x0,x1) x0 += k1; x1 += k2 + 1u;
  TF_ROUNDS_B(x0,x1) x0 += k2; x1 += k0 + 2u;
  TF_ROUNDS_A(x0,x1) x0 += k0; x1 += k1 + 3u;
  TF_ROUNDS_B(x0,x1) x0 += k1; x1 += k2 + 4u;
  TF_ROUNDS_A(x0,x1) x0 += k2; x1 += k0 + 5u;
  o0 = x0; o1 = x1;
}

__device__ __forceinline__ float jax_normal32(uint32_t k0, uint32_t k1, uint32_t idx) {
  uint32_t o0, o1;
  threefry2x32(k0, k1, 0u, idx, o0, o1);
  uint32_t bits = o0 ^ o1;
  float u01 = __uint_as_float((bits >> 9) | 0x3f800000u) - 1.0f;
  float u = __fadd_rn(__fmul_rn(u01, 2.0f), -0.99999994f);
  u = fmaxf(u, -0.99999994f);
  float xx = __fmul_rn(u, u);
  float w = -log1pf(-xx);
  float p;
  if (w < 5.0f) {
    w = __fadd_rn(w, -2.5f);
    p =                2.81022636e-08f;
    p = __fadd_rn( 3.43273939e-07f, __fmul_rn(p, w));
    p = __fadd_rn(-3.5233877e-06f,  __fmul_rn(p, w));
    p = __fadd_rn(-4.39150654e-06f, __fmul_rn(p, w));
    p = __fadd_rn( 0.00021858087f,  __fmul_rn(p, w));
    p = __fadd_rn(-0.00125372503f,  __fmul_rn(p, w));
    p = __fadd_rn(-0.00417768164f,  __fmul_rn(p, w));
    p = __fadd_rn( 0.246640727f,    __fmul_rn(p, w));
    p = __fadd_rn( 1.50140941f,     __fmul_rn(p, w));
  } else {
    w = __fadd_rn(__fsqrt_rn(w), -3.0f);
    p =               -0.000200214257f;
    p = __fadd_rn( 0.000100950558f, __fmul_rn(p, w));
    p = __fadd_rn( 0.00134934322f,  __fmul_rn(p, w));
    p = __fadd_rn(-0.00367342844f,  __fmul_rn(p, w));
    p = __fadd_rn( 0.00573950773f,  __fmul_rn(p, w));
    p = __fadd_rn(-0.0076224613f,   __fmul_rn(p, w));
    p = __fadd_rn( 0.00943887047f,  __fmul_rn(p, w));
    p = __fadd_rn( 1.00167406f,     __fmul_rn(p, w));
    p = __fadd_rn( 2.83297682f,     __fmul_rn(p, w));
  }
  return __fmul_rn(1.41421356f, __fmul_rn(p, u));
}

__device__ __forceinline__ float softplus_ref(float x) {
  float l = log1pf(expf(fminf(x, 20.0f)));
  return (x > 20.0f) ? x : l;
}

// ---- pre-kernel: dst = softplus(src)^2, float4 grid-stride ----
__global__ void softplus2_kernel(const float* __restrict__ src,
                                 float* __restrict__ dst, int n4) {
  int i = blockIdx.x * blockDim.x + threadIdx.x;
  const int stride = gridDim.x * blockDim.x;
  for (; i < n4; i += stride) {
    float4 v = ((const float4*)src)[i];
    float a = softplus_ref(v.x), b = softplus_ref(v.y);
    float c = softplus_ref(v.z), d = softplus_ref(v.w);
    ((float4*)dst)[i] = make_float4(__fmul_rn(a, a), __fmul_rn(b, b),
                                    __fmul_rn(c, c), __fmul_rn(d, d));
  }
}

// hT swizzle (16-row tile): idx = col*16 + (row ^ (((col>>3)&7)<<1))
#define HT_IDX(col, row) (((col) << 4) + ((row) ^ ((((col) >> 3) & 7) << 1)))

// MODE 0: variance weights precomputed in ws. MODE 1: inline softplus staging.
template<int MODE>
__global__ __launch_bounds__(256, 4)
void vsiren_kernel(const float* __restrict__ X,
                   const float* __restrict__ mu0, const float* __restrict__ ls0,
                   const float* __restrict__ mu1, const float* __restrict__ ls1,
                   const float* __restrict__ mu2, const float* __restrict__ ls2,
                   const float* __restrict__ mu3, const float* __restrict__ ls3,
                   const float* __restrict__ mu4, const float* __restrict__ ls4,
                   const float* __restrict__ ws,
                   float* __restrict__ out, Keys keys)
{
  __shared__ float hTf[256 * NTILE];                    // 16 KB
  __shared__ float s2b[(MODE == 1) ? 8 * 256 : 4];      // 8 KB in MODE1

  const int tid = threadIdx.x;
  const uint32_t bid = blockIdx.x;
  const uint32_t swz = (bid & 7u) * (NBLOCKS / 8) + (bid >> 3);   // XCD swizzle
  const int s  = (int)(swz >> 9);
  const int n0 = (int)(swz & 511u) * NTILE;

  // ---- posenc (direct X load, no LDS staging) ----
  {
    const int r = tid & 15, p = tid >> 4;
    const int d = p & 1, trg = (p >> 1) & 1, kh = p >> 2;   // kh in 0..3
    const float xv = X[(size_t)(s * NPTS + n0 + r) * 2 + d];
    const float delta = 6.93147182464599609375f / 63.0f;
    #pragma unroll 4
    for (int j = 0; j < 16; ++j) {
      const int kf = kh * 16 + j;
      const int f = trg * 128 + d * 64 + kf;
      float w = expf(__fmul_rn((float)kf, delta));
      float arg = __fmul_rn(3.14159274101257324f, __fmul_rn(xv, w));
      hTf[HT_IDX(f, r)] = trg ? sinf(arg) : cosf(arg);
    }
  }
  __syncthreads();

  const int tc = tid & 31;          // col group: cols tc*8..tc*8+7
  const int tr = tid >> 5;          // row group: rows tr*2..tr*2+1
  const int rowA = tr * 2;

  // s2b chunk swizzle (MODE1 only): 16B-chunk c stored at c ^ ((c>>3)&7)
  const int c0 = 2 * tc, c1 = 2 * tc + 1;
  const int so0 = (c0 ^ ((c0 >> 3) & 7)) * 4;
  const int so1 = (c1 ^ ((c1 >> 3) & 7)) * 4;

  #pragma unroll 1
  for (int l = 0; l < 4; ++l) {
    const float* __restrict__ mu =
        ((l == 0) ? mu0 : (l == 1) ? mu1 : (l == 2) ? mu2 : mu3) + (size_t)s * (257 * 256);
    const float* __restrict__ ls =
        ((l == 0) ? ls0 : (l == 1) ? ls1 : (l == 2) ? ls2 : ls3) + (size_t)s * (257 * 256);
    const float* __restrict__ qw =
        (MODE == 0) ? (ws + (size_t)l * WS_L + (size_t)s * (257 * 256)) : nullptr;
    const uint32_t lk0 = (l == 0) ? keys.k0[0] : (l == 1) ? keys.k0[1] : (l == 2) ? keys.k0[2] : keys.k0[3];
    const uint32_t lk1 = (l == 0) ? keys.k1[0] : (l == 1) ? keys.k1[1] : (l == 2) ? keys.k1[2] : keys.k1[3];

    float am[2][8], av[2][8];
    #pragma unroll
    for (int i = 0; i < 2; ++i)
      #pragma unroll
      for (int j = 0; j < 8; ++j) { am[i][j] = 0.f; av[i][j] = 0.f; }

    #pragma unroll 1
    for (int ch = 0; ch < 32; ++ch) {
      if constexpr (MODE == 1) {
        __syncthreads();
        // stage softplus(ls)^2 for 8 k-rows x 256 cols
        const float* lsrow = ls + (size_t)(ch * 8 + (tid >> 5)) * 256 + tc * 8;
        const float4 l0v = *(const float4*)lsrow;
        const float4 l1v = *(const float4*)(lsrow + 4);
        float a0 = softplus_ref(l0v.x), a1 = softplus_ref(l0v.y);
        float a2 = softplus_ref(l0v.z), a3 = softplus_ref(l0v.w);
        float b0 = softplus_ref(l1v.x), b1 = softplus_ref(l1v.y);
        float b2 = softplus_ref(l1v.z), b3 = softplus_ref(l1v.w);
        float* dst = &s2b[(tid >> 5) * 256];
        *(float4*)(dst + so0) = make_float4(__fmul_rn(a0, a0), __fmul_rn(a1, a1),
                                            __fmul_rn(a2, a2), __fmul_rn(a3, a3));
        *(float4*)(dst + so1) = make_float4(__fmul_rn(b0, b0), __fmul_rn(b1, b1),
                                            __fmul_rn(b2, b2), __fmul_rn(b3, b3));
        __syncthreads();
      }

      const float* ab = &hTf[(ch * 8) * 16 + (rowA ^ ((ch & 7) << 1))];
      const float* wb = mu + (size_t)(ch * 8) * 256 + tc * 8;
      const float* qb = (MODE == 0) ? (qw + (size_t)(ch * 8) * 256 + tc * 8) : nullptr;

      #pragma unroll
      for (int kk = 0; kk < 8; ++kk) {
        const float2 a  = *(const float2*)(ab + kk * 16);
        const float4 w0 = *(const float4*)(wb + kk * 256);
        const float4 w1 = *(const float4*)(wb + kk * 256 + 4);
        float4 q0, q1;
        if constexpr (MODE == 0) {
          q0 = *(const float4*)(qb + kk * 256);
          q1 = *(const float4*)(qb + kk * 256 + 4);
        } else {
          q0 = *(const float4*)(&s2b[kk * 256] + so0);
          q1 = *(const float4*)(&s2b[kk * 256] + so1);
        }
        const float ar[2] = {a.x, a.y};
        const float wm[8] = {w0.x, w0.y, w0.z, w0.w, w1.x, w1.y, w1.z, w1.w};
        const float wsq[8] = {q0.x, q0.y, q0.z, q0.w, q1.x, q1.y, q1.z, q1.w};
        #pragma unroll
        for (int rr = 0; rr < 2; ++rr) {
          const float hv = ar[rr];
          const float h2 = __fmul_rn(hv, hv);
          #pragma unroll
          for (int c = 0; c < 8; ++c) {
            am[rr][c] = fmaf(hv, wm[c], am[rr][c]);
            av[rr][c] = fmaf(h2, wsq[c], av[rr][c]);
          }
        }
      }
    }

    // ---- epilogue: bias, variance, noise, sin — results overwrite am ----
    {
      const float* mub_p = mu + 256 * 256;
      #pragma unroll
      for (int c = 0; c < 8; ++c) {
        const int col = tc * 8 + c;
        const float mub = mub_p[col];
        float vb;
        if constexpr (MODE == 0) {
          vb = qw[256 * 256 + col];
        } else {
          const float spb = softplus_ref(ls[(size_t)256 * 256 + col]);
          vb = __fmul_rn(spb, spb);
        }
        #pragma unroll
        for (int rr = 0; rr < 2; ++rr) {
          float m   = __fadd_rn(am[rr][c], mub);
          float var = __fadd_rn(__fadd_rn(av[rr][c], vb), 1e-14f);
          float sv  = __fsqrt_rn(var);
          uint32_t idx = ((uint32_t)(s * NPTS + n0 + rowA + rr)) * 256u + (uint32_t)col;
          float nz = jax_normal32(lk0, lk1, idx);
          float z  = __fadd_rn(m, __fmul_rn(sv, nz));
          am[rr][c] = sinf(__fmul_rn(30.0f, z));
        }
      }
    }
    __syncthreads();               // all hT reads for this layer done
    {
      const int wrow = rowA ^ ((tc & 7) << 1);
      #pragma unroll
      for (int c = 0; c < 8; ++c) {
        *(float2*)&hTf[((tc * 8 + c) << 4) + wrow] = make_float2(am[0][c], am[1][c]);
      }
    }
    __syncthreads();
  } // layer

  // ---- layer 4: 256 -> 3, last=True (no sin) ----
  {
    const float* __restrict__ mu = mu4 + (size_t)s * (257 * 3);
    const float* __restrict__ ls = ls4 + (size_t)s * (257 * 3);
    const float* __restrict__ q4 =
        (MODE == 0) ? (ws + WS_L4 + (size_t)s * 771) : nullptr;
    float* s2w = nullptr;
    if constexpr (MODE == 1) {
      s2w = &s2b[0];
      for (int e = tid; e < 771; e += 256) {
        float sp = softplus_ref(ls[e]);
        s2w[e] = __fmul_rn(sp, sp);
      }
      __syncthreads();
    }

    const int r = tid >> 4, o = tid & 15;
    if (o < 3) {
      float am = 0.f, av2 = 0.f;
      #pragma unroll 4
      for (int k = 0; k < 256; ++k) {
        float hv = hTf[HT_IDX(k, r)];
        float sq = (MODE == 0) ? q4[k * 3 + o] : s2w[k * 3 + o];
        am  = fmaf(hv, mu[k * 3 + o], am);
        av2 = fmaf(__fmul_rn(hv, hv), sq, av2);
      }
      float bsq = (MODE == 0) ? q4[256 * 3 + o] : s2w[256 * 3 + o];
      float m   = __fadd_rn(am, mu[256 * 3 + o]);
      float var = __fadd_rn(__fadd_rn(av2, bsq), 1e-14f);
      float sv  = __fsqrt_rn(var);
      const int n = n0 + r;
      uint32_t idx = ((uint32_t)(s * NPTS + n)) * 3u + (uint32_t)o;
      float nz = jax_normal32(keys.k0[4], keys.k1[4], idx);
      out[(size_t)(s * NPTS + n) * 3 + o] = __fadd_rn(m, __fmul_rn(sv, nz));
    }
  }
}

extern "C" void kernel_launch(void* const* d_in, const int* in_sizes, int n_in,
                              void* d_out, int out_size, void* d_ws, size_t ws_size,
                              hipStream_t stream) {
  (void)in_sizes; (void)n_in; (void)out_size;
  const float* X   = (const float*)d_in[0];
  const float* mu0 = (const float*)d_in[1];
  const float* ls0 = (const float*)d_in[2];
  const float* mu1 = (const float*)d_in[3];
  const float* ls1 = (const float*)d_in[4];
  const float* mu2 = (const float*)d_in[5];
  const float* ls2 = (const float*)d_in[6];
  const float* mu3 = (const float*)d_in[7];
  const float* ls3 = (const float*)d_in[8];
  const float* mu4 = (const float*)d_in[9];
  const float* ls4 = (const float*)d_in[10];

  Keys keys;
  for (int l = 0; l < 5; ++l) {
    uint32_t o0, o1;
    threefry2x32(0u, 42u, 0u, (uint32_t)l, o0, o1);
    keys.k0[l] = o0; keys.k1[l] = o1;
  }

  const bool pre = (d_ws != nullptr) && (ws_size >= WS_BYTES);
  if (pre) {
    float* ws = (float*)d_ws;
    const float* lsp[4] = {ls0, ls1, ls2, ls3};
    for (int l = 0; l < 4; ++l)
      softplus2_kernel<<<dim3(2048), dim3(256), 0, stream>>>(
          lsp[l], ws + (size_t)l * WS_L, WS_L / 4);
    softplus2_kernel<<<dim3(64), dim3(256), 0, stream>>>(
        ls4, ws + WS_L4, (WS_TOT - WS_L4) / 4);
    vsiren_kernel<0><<<dim3(NBLOCKS), dim3(256), 0, stream>>>(
        X, mu0, ls0, mu1, ls1, mu2, ls2, mu3, ls3, mu4, ls4,
        ws, (float*)d_out, keys);
  } else {
    vsiren_kernel<1><<<dim3(NBLOCKS), dim3(256), 0, stream>>>(
        X, mu0, ls0, mu1, ls1, mu2, ls2, mu3, ls3, mu4, ls4,
        nullptr, (float*)d_out, keys);
  }
}

// Round 5
// 7993.687 us; speedup vs baseline: 5.7082x; 2.0625x over previous
//
#include <hip/hip_runtime.h>
#include <hip/hip_bf16.h>
#include <stdint.h>

#define NSIZE   64
#define NPTS    8192

struct Keys { uint32_t k0[5]; uint32_t k1[5]; };

typedef unsigned short ushort_t;
typedef __attribute__((ext_vector_type(8))) short bh8;
typedef __attribute__((ext_vector_type(4))) float f32x4;

// ---------------- threefry2x32, 20 rounds (JAX-compatible) ----------------
#define TF_ROUNDS_A(x0,x1) \
  x0 += x1; x1 = (x1<<13)|(x1>>19); x1 ^= x0; \
  x0 += x1; x1 = (x1<<15)|(x1>>17); x1 ^= x0; \
  x0 += x1; x1 = (x1<<26)|(x1>>6);  x1 ^= x0; \
  x0 += x1; x1 = (x1<<6) |(x1>>26); x1 ^= x0;
#define TF_ROUNDS_B(x0,x1) \
  x0 += x1; x1 = (x1<<17)|(x1>>15); x1 ^= x0; \
  x0 += x1; x1 = (x1<<29)|(x1>>3);  x1 ^= x0; \
  x0 += x1; x1 = (x1<<16)|(x1>>16); x1 ^= x0; \
  x0 += x1; x1 = (x1<<24)|(x1>>8);  x1 ^= x0;

__host__ __device__ inline void threefry2x32(uint32_t k0, uint32_t k1,
                                             uint32_t c0, uint32_t c1,
                                             uint32_t& o0, uint32_t& o1) {
  uint32_t k2 = k0 ^ k1 ^ 0x1BD11BDAu;
  uint32_t x0 = c0 + k0, x1 = c1 + k1;
  TF_ROUNDS_A(x0,x1) x0 += k1; x1 += k2 + 1u;
  TF_ROUNDS_B(x0,x1) x0 += k2; x1 += k0 + 2u;
  TF_ROUNDS_A(x0,x1) x0 += k0; x1 += k1 + 3u;
  TF_ROUNDS_B(x0,x1) x0 += k1; x1 += k2 + 4u;
  TF_ROUNDS_A(x0,x1) x0 += k2; x1 += k0 + 5u;
  o0 = x0; o1 = x1;
}

__device__ __forceinline__ float jax_normal32(uint32_t k0, uint32_t k1, uint32_t idx) {
  uint32_t o0, o1;
  threefry2x32(k0, k1, 0u, idx, o0, o1);
  uint32_t bits = o0 ^ o1;
  float u01 = __uint_as_float((bits >> 9) | 0x3f800000u) - 1.0f;
  float u = __fadd_rn(__fmul_rn(u01, 2.0f), -0.99999994f);
  u = fmaxf(u, -0.99999994f);
  float xx = __fmul_rn(u, u);
  float w = -log1pf(-xx);
  float p;
  if (w < 5.0f) {
    w = __fadd_rn(w, -2.5f);
    p =                2.81022636e-08f;
    p = __fadd_rn( 3.43273939e-07f, __fmul_rn(p, w));
    p = __fadd_rn(-3.5233877e-06f,  __fmul_rn(p, w));
    p = __fadd_rn(-4.39150654e-06f, __fmul_rn(p, w));
    p = __fadd_rn( 0.00021858087f,  __fmul_rn(p, w));
    p = __fadd_rn(-0.00125372503f,  __fmul_rn(p, w));
    p = __fadd_rn(-0.00417768164f,  __fmul_rn(p, w));
    p = __fadd_rn( 0.246640727f,    __fmul_rn(p, w));
    p = __fadd_rn( 1.50140941f,     __fmul_rn(p, w));
  } else {
    w = __fadd_rn(__fsqrt_rn(w), -3.0f);
    p =               -0.000200214257f;
    p = __fadd_rn( 0.000100950558f, __fmul_rn(p, w));
    p = __fadd_rn( 0.00134934322f,  __fmul_rn(p, w));
    p = __fadd_rn(-0.00367342844f,  __fmul_rn(p, w));
    p = __fadd_rn( 0.00573950773f,  __fmul_rn(p, w));
    p = __fadd_rn(-0.0076224613f,   __fmul_rn(p, w));
    p = __fadd_rn( 0.00943887047f,  __fmul_rn(p, w));
    p = __fadd_rn( 1.00167406f,     __fmul_rn(p, w));
    p = __fadd_rn( 2.83297682f,     __fmul_rn(p, w));
  }
  return __fmul_rn(1.41421356f, __fmul_rn(p, u));
}

__device__ __forceinline__ float softplus_ref(float x) {
  float l = log1pf(expf(fminf(x, 20.0f)));
  return (x > 20.0f) ? x : l;
}

// ================= MFMA path =================
// ws layout (ushort idx): MH 0 | ML 16777216 | QH 33554432 | QL 50331648
// then f32 region at byte 134217728: q2_b[4*64*256], q4[64*771]
#define U_MH 0u
#define U_ML 16777216u
#define U_QH 33554432u
#define WSF_BYTE_OFF 134217728u
#define WS_NEED (134217728ull + (65536ull + 49344ull) * 4ull)

// transpose+split weights: bid = ((arr*4 + l)*64 + s)*8 + kc   (grid 4096)
__global__ __launch_bounds__(256)
void prep_tsplit(const float* __restrict__ mu0, const float* __restrict__ mu1,
                 const float* __restrict__ mu2, const float* __restrict__ mu3,
                 const float* __restrict__ ls0, const float* __restrict__ ls1,
                 const float* __restrict__ ls2, const float* __restrict__ ls3,
                 ushort_t* __restrict__ wsu)
{
  const int bid = blockIdx.x;
  const int kc = bid & 7, s = (bid >> 3) & 63, l = (bid >> 9) & 3, arr = bid >> 11;
  const float* src =
      (l == 0) ? (arr ? ls0 : mu0) : (l == 1) ? (arr ? ls1 : mu1)
    : (l == 2) ? (arr ? ls2 : mu2) : (arr ? ls3 : mu3);
  src += (size_t)s * 65792 + (size_t)kc * 32 * 256;
  ushort_t* dhi = wsu + (arr ? U_QH : U_MH) + (size_t)(l * 64 + s) * 65536 + kc * 32;
  ushort_t* dlo = dhi + U_ML;   // lo region is +16777216 for both mu and q2

  __shared__ float tile[32][260];
  const int t = threadIdx.x;
  #pragma unroll 8
  for (int rr = 0; rr < 32; ++rr) tile[rr][t] = src[rr * 256 + t];
  __syncthreads();

  __align__(16) ushort_t hib[32], lob[32];
  #pragma unroll 8
  for (int kk = 0; kk < 32; ++kk) {
    float v = tile[kk][t];
    if (arr) { float sp = softplus_ref(v); v = __fmul_rn(sp, sp); }
    __hip_bfloat16 hb = __float2bfloat16(v);
    float hf = __bfloat162float(hb);
    __hip_bfloat16 lb = __float2bfloat16(__fsub_rn(v, hf));
    hib[kk] = *(ushort_t*)&hb;
    lob[kk] = *(ushort_t*)&lb;
  }
  ushort_t* ph = dhi + (size_t)t * 256;
  ushort_t* pl = dlo + (size_t)t * 256;
  #pragma unroll
  for (int i = 0; i < 4; ++i) {
    *(uint4*)(ph + i * 8) = *(const uint4*)(hib + i * 8);
    *(uint4*)(pl + i * 8) = *(const uint4*)(lob + i * 8);
  }
}

// biases: bid<256 -> q2_b for (l,s); bid 256..319 -> layer4 q4   (grid 320)
__global__ __launch_bounds__(256)
void prep_bias(const float* __restrict__ ls0, const float* __restrict__ ls1,
               const float* __restrict__ ls2, const float* __restrict__ ls3,
               const float* __restrict__ ls4, float* __restrict__ wsf)
{
  const int bid = blockIdx.x, t = threadIdx.x;
  if (bid < 256) {
    const int l = bid >> 6, s = bid & 63;
    const float* ls = ((l == 0) ? ls0 : (l == 1) ? ls1 : (l == 2) ? ls2 : ls3)
                      + (size_t)s * 65792 + 65536;
    float sp = softplus_ref(ls[t]);
    wsf[(size_t)(l * 64 + s) * 256 + t] = __fmul_rn(sp, sp);
  } else {
    const int s = bid - 256;
    for (int e = t; e < 771; e += 256) {
      float sp = softplus_ref(ls4[(size_t)s * 771 + e]);
      wsf[65536 + (size_t)s * 771 + e] = __fmul_rn(sp, sp);
    }
  }
}

// main MFMA kernel: 512 thr (8 waves), 32 rows/block, wave w -> coltiles {2w,2w+1}
__global__ __launch_bounds__(512, 2)
void vsiren_mfma(const float* __restrict__ X,
                 const float* __restrict__ mu0, const float* __restrict__ mu1,
                 const float* __restrict__ mu2, const float* __restrict__ mu3,
                 const float* __restrict__ mu4,
                 const ushort_t* __restrict__ wsu, const float* __restrict__ wsf,
                 float* __restrict__ out, Keys keys)
{
  __shared__ ushort_t hhi[8192], hlo[8192], hsq[8192];   // 3 x 16 KB, XOR-swizzled
  const int tid = threadIdx.x;
  const int w = tid >> 6, lane = tid & 63, lr = lane & 15, g = lane >> 4;
  const uint32_t bid = blockIdx.x;
  const uint32_t swz = (bid & 7u) * 2048u + (bid >> 3);   // XCD swizzle
  const int s  = (int)(swz >> 8);
  const int n0 = (int)(swz & 255u) * 32;

  // ---- posenc -> LDS (hi, lo, sq) ----
  {
    const int r = tid & 31, p = tid >> 5;
    const float x0 = X[(size_t)(s * NPTS + n0 + r) * 2 + 0];
    const float x1 = X[(size_t)(s * NPTS + n0 + r) * 2 + 1];
    const float delta = 6.93147182464599609375f / 63.0f;
    const int xsh = (r & 7) << 3;
    #pragma unroll 4
    for (int jj = 0; jj < 16; ++jj) {
      const int f = p * 16 + jj;
      const int trg = f >> 7, d = (f >> 6) & 1, kf = f & 63;
      const float xv = d ? x1 : x0;
      float wf = expf(__fmul_rn((float)kf, delta));
      float arg = __fmul_rn(3.14159274101257324f, __fmul_rn(xv, wf));
      float v = trg ? sinf(arg) : cosf(arg);
      __hip_bfloat16 hb = __float2bfloat16(v);
      float hf = __bfloat162float(hb);
      __hip_bfloat16 lb = __float2bfloat16(__fsub_rn(v, hf));
      __hip_bfloat16 qv = __float2bfloat16(__fmul_rn(v, v));
      const int wi = r * 256 + (f ^ xsh);
      hhi[wi] = *(ushort_t*)&hb; hlo[wi] = *(ushort_t*)&lb; hsq[wi] = *(ushort_t*)&qv;
    }
  }
  __syncthreads();

  const int c0 = w * 32 + lr;

  #pragma unroll 1
  for (int l = 0; l < 4; ++l) {
    const size_t wb = (size_t)(l * 64 + s) * 65536;
    const ushort_t* mh = wsu + U_MH + wb;
    const ushort_t* ml = wsu + U_ML + wb;
    const ushort_t* qh = wsu + U_QH + wb;
    const ushort_t* ql = wsu + U_QH + U_ML + wb;
    const float* mubp = ((l == 0) ? mu0 : (l == 1) ? mu1 : (l == 2) ? mu2 : mu3)
                        + (size_t)s * 65792 + 65536;
    const float* qbp = wsf + (size_t)(l * 64 + s) * 256;
    const uint32_t lk0 = (l == 0) ? keys.k0[0] : (l == 1) ? keys.k0[1] : (l == 2) ? keys.k0[2] : keys.k0[3];
    const uint32_t lk1 = (l == 0) ? keys.k1[0] : (l == 1) ? keys.k1[1] : (l == 2) ? keys.k1[2] : keys.k1[3];

    f32x4 am[2][2], av[2][2];
    #pragma unroll
    for (int a = 0; a < 2; ++a)
      #pragma unroll
      for (int b = 0; b < 2; ++b) {
        am[a][b] = (f32x4){0.f, 0.f, 0.f, 0.f};
        av[a][b] = (f32x4){0.f, 0.f, 0.f, 0.f};
      }

    #pragma unroll 2
    for (int ks = 0; ks < 8; ++ks) {
      bh8 Ahi[2], Alo[2], Asq[2];
      #pragma unroll
      for (int b = 0; b < 2; ++b) {
        const int rl = b * 16 + lr;
        const int ri = rl * 256 + ((ks * 32 + g * 8) ^ ((rl & 7) << 3));
        Ahi[b] = *(const bh8*)&hhi[ri];
        Alo[b] = *(const bh8*)&hlo[ri];
        Asq[b] = *(const bh8*)&hsq[ri];
      }
      #pragma unroll
      for (int ct = 0; ct < 2; ++ct) {
        const size_t eo = (size_t)(c0 + ct * 16) * 256 + (size_t)(ks * 32 + g * 8);
        const bh8 WH = *(const bh8*)&mh[eo];
        const bh8 WL = *(const bh8*)&ml[eo];
        const bh8 QH = *(const bh8*)&qh[eo];
        const bh8 QL = *(const bh8*)&ql[eo];
        #pragma unroll
        for (int b = 0; b < 2; ++b) {
          am[ct][b] = __builtin_amdgcn_mfma_f32_16x16x32_bf16(Ahi[b], WH, am[ct][b], 0, 0, 0);
          am[ct][b] = __builtin_amdgcn_mfma_f32_16x16x32_bf16(Alo[b], WH, am[ct][b], 0, 0, 0);
          am[ct][b] = __builtin_amdgcn_mfma_f32_16x16x32_bf16(Ahi[b], WL, am[ct][b], 0, 0, 0);
          av[ct][b] = __builtin_amdgcn_mfma_f32_16x16x32_bf16(Asq[b], QH, av[ct][b], 0, 0, 0);
          av[ct][b] = __builtin_amdgcn_mfma_f32_16x16x32_bf16(Asq[b], QL, av[ct][b], 0, 0, 0);
        }
      }
    }
    __syncthreads();   // all LDS A-reads for this layer done

    // ---- epilogue: bias, variance, noise, sin -> write h arrays ----
    #pragma unroll
    for (int ct = 0; ct < 2; ++ct) {
      const int c = c0 + ct * 16;
      const float mub = mubp[c];
      const float qb2 = qbp[c];
      #pragma unroll
      for (int b = 0; b < 2; ++b) {
        #pragma unroll
        for (int j = 0; j < 4; ++j) {
          const int rl = b * 16 + g * 4 + j;
          float m   = __fadd_rn(am[ct][b][j], mub);
          float var = __fadd_rn(__fadd_rn(av[ct][b][j], qb2), 1e-14f);
          float sv  = __fsqrt_rn(var);
          uint32_t idx = ((uint32_t)(s * NPTS + n0 + rl)) * 256u + (uint32_t)c;
          float nz = jax_normal32(lk0, lk1, idx);
          float z  = __fadd_rn(m, __fmul_rn(sv, nz));
          float a  = sinf(__fmul_rn(30.0f, z));
          __hip_bfloat16 hb = __float2bfloat16(a);
          float hf = __bfloat162float(hb);
          __hip_bfloat16 lb = __float2bfloat16(__fsub_rn(a, hf));
          __hip_bfloat16 sq = __float2bfloat16(__fmul_rn(a, a));
          const int wi = rl * 256 + (c ^ ((rl & 7) << 3));
          hhi[wi] = *(ushort_t*)&hb; hlo[wi] = *(ushort_t*)&lb; hsq[wi] = *(ushort_t*)&sq;
        }
      }
    }
    __syncthreads();
  } // layer

  // ---- layer 4: 256 -> 3 (no sin), k split 4-way + shfl reduce ----
  {
    const int r = tid >> 4, o = tid & 3, q = (tid >> 2) & 3;
    const float* m4 = mu4 + (size_t)s * 771;
    const float* q4 = wsf + 65536 + (size_t)s * 771;
    const int oo = (o < 3) ? o : 0;
    const int xsh = (r & 7) << 3;
    float am4 = 0.f, av4 = 0.f;
    #pragma unroll 4
    for (int kk = 0; kk < 64; ++kk) {
      const int k = q * 64 + kk;
      const int ri = r * 256 + (k ^ xsh);
      float hv = __fadd_rn(__bfloat162float(*(const __hip_bfloat16*)&hhi[ri]),
                           __bfloat162float(*(const __hip_bfloat16*)&hlo[ri]));
      am4 = fmaf(hv, m4[k * 3 + oo], am4);
      av4 = fmaf(__fmul_rn(hv, hv), q4[k * 3 + oo], av4);
    }
    am4 = __fadd_rn(am4, __shfl_xor(am4, 4));
    am4 = __fadd_rn(am4, __shfl_xor(am4, 8));
    av4 = __fadd_rn(av4, __shfl_xor(av4, 4));
    av4 = __fadd_rn(av4, __shfl_xor(av4, 8));
    if (o < 3 && q == 0) {
      float m   = __fadd_rn(am4, m4[768 + o]);
      float var = __fadd_rn(__fadd_rn(av4, q4[768 + o]), 1e-14f);
      float sv  = __fsqrt_rn(var);
      const int n = n0 + r;
      uint32_t idx = ((uint32_t)(s * NPTS + n)) * 3u + (uint32_t)o;
      float nz = jax_normal32(keys.k0[4], keys.k1[4], idx);
      out[(size_t)(s * NPTS + n) * 3 + o] = __fadd_rn(m, __fmul_rn(sv, nz));
    }
  }
}

// ================= fallback (round-4) path =================
#define FB_NTILE 16
#define FB_NBLOCKS (NSIZE * (NPTS / FB_NTILE))
#define FB_WS_L    4210688
#define FB_WS_L4   16842752
#define FB_WS_TOT  16892096
#define FB_WS_BYTES ((size_t)FB_WS_TOT * 4)

__global__ void softplus2_kernel(const float* __restrict__ src,
                                 float* __restrict__ dst, int n4) {
  int i = blockIdx.x * blockDim.x + threadIdx.x;
  const int stride = gridDim.x * blockDim.x;
  for (; i < n4; i += stride) {
    float4 v = ((const float4*)src)[i];
    float a = softplus_ref(v.x), b = softplus_ref(v.y);
    float c = softplus_ref(v.z), d = softplus_ref(v.w);
    ((float4*)dst)[i] = make_float4(__fmul_rn(a, a), __fmul_rn(b, b),
                                    __fmul_rn(c, c), __fmul_rn(d, d));
  }
}

#define HT_IDX(col, row) (((col) << 4) + ((row) ^ ((((col) >> 3) & 7) << 1)))

template<int MODE>
__global__ __launch_bounds__(256, 2)
void vsiren_fb(const float* __restrict__ X,
               const float* __restrict__ mu0, const float* __restrict__ ls0,
               const float* __restrict__ mu1, const float* __restrict__ ls1,
               const float* __restrict__ mu2, const float* __restrict__ ls2,
               const float* __restrict__ mu3, const float* __restrict__ ls3,
               const float* __restrict__ mu4, const float* __restrict__ ls4,
               const float* __restrict__ ws,
               float* __restrict__ out, Keys keys)
{
  __shared__ float hTf[256 * FB_NTILE];
  __shared__ float s2b[(MODE == 1) ? 8 * 256 : 4];

  const int tid = threadIdx.x;
  const uint32_t bid = blockIdx.x;
  const uint32_t swz = (bid & 7u) * (FB_NBLOCKS / 8) + (bid >> 3);
  const int s  = (int)(swz >> 9);
  const int n0 = (int)(swz & 511u) * FB_NTILE;

  {
    const int r = tid & 15, p = tid >> 4;
    const int d = p & 1, trg = (p >> 1) & 1, kh = p >> 2;
    const float xv = X[(size_t)(s * NPTS + n0 + r) * 2 + d];
    const float delta = 6.93147182464599609375f / 63.0f;
    #pragma unroll 4
    for (int j = 0; j < 16; ++j) {
      const int kf = kh * 16 + j;
      const int f = trg * 128 + d * 64 + kf;
      float w = expf(__fmul_rn((float)kf, delta));
      float arg = __fmul_rn(3.14159274101257324f, __fmul_rn(xv, w));
      hTf[HT_IDX(f, r)] = trg ? sinf(arg) : cosf(arg);
    }
  }
  __syncthreads();

  const int tc = tid & 31;
  const int tr = tid >> 5;
  const int rowA = tr * 2;
  const int c0 = 2 * tc, c1 = 2 * tc + 1;
  const int so0 = (c0 ^ ((c0 >> 3) & 7)) * 4;
  const int so1 = (c1 ^ ((c1 >> 3) & 7)) * 4;

  #pragma unroll 1
  for (int l = 0; l < 4; ++l) {
    const float* __restrict__ mu =
        ((l == 0) ? mu0 : (l == 1) ? mu1 : (l == 2) ? mu2 : mu3) + (size_t)s * (257 * 256);
    const float* __restrict__ ls =
        ((l == 0) ? ls0 : (l == 1) ? ls1 : (l == 2) ? ls2 : ls3) + (size_t)s * (257 * 256);
    const float* __restrict__ qw =
        (MODE == 0) ? (ws + (size_t)l * FB_WS_L + (size_t)s * (257 * 256)) : nullptr;
    const uint32_t lk0 = (l == 0) ? keys.k0[0] : (l == 1) ? keys.k0[1] : (l == 2) ? keys.k0[2] : keys.k0[3];
    const uint32_t lk1 = (l == 0) ? keys.k1[0] : (l == 1) ? keys.k1[1] : (l == 2) ? keys.k1[2] : keys.k1[3];

    float am[2][8], av[2][8];
    #pragma unroll
    for (int i = 0; i < 2; ++i)
      #pragma unroll
      for (int j = 0; j < 8; ++j) { am[i][j] = 0.f; av[i][j] = 0.f; }

    #pragma unroll 1
    for (int ch = 0; ch < 32; ++ch) {
      if constexpr (MODE == 1) {
        __syncthreads();
        const float* lsrow = ls + (size_t)(ch * 8 + (tid >> 5)) * 256 + tc * 8;
        const float4 l0v = *(const float4*)lsrow;
        const float4 l1v = *(const float4*)(lsrow + 4);
        float a0 = softplus_ref(l0v.x), a1 = softplus_ref(l0v.y);
        float a2 = softplus_ref(l0v.z), a3 = softplus_ref(l0v.w);
        float b0 = softplus_ref(l1v.x), b1 = softplus_ref(l1v.y);
        float b2 = softplus_ref(l1v.z), b3 = softplus_ref(l1v.w);
        float* dst = &s2b[(tid >> 5) * 256];
        *(float4*)(dst + so0) = make_float4(__fmul_rn(a0, a0), __fmul_rn(a1, a1),
                                            __fmul_rn(a2, a2), __fmul_rn(a3, a3));
        *(float4*)(dst + so1) = make_float4(__fmul_rn(b0, b0), __fmul_rn(b1, b1),
                                            __fmul_rn(b2, b2), __fmul_rn(b3, b3));
        __syncthreads();
      }

      const float* ab = &hTf[(ch * 8) * 16 + (rowA ^ ((ch & 7) << 1))];
      const float* wb = mu + (size_t)(ch * 8) * 256 + tc * 8;
      const float* qb = (MODE == 0) ? (qw + (size_t)(ch * 8) * 256 + tc * 8) : nullptr;

      #pragma unroll
      for (int kk = 0; kk < 8; ++kk) {
        const float2 a  = *(const float2*)(ab + kk * 16);
        const float4 w0 = *(const float4*)(wb + kk * 256);
        const float4 w1 = *(const float4*)(wb + kk * 256 + 4);
        float4 q0, q1;
        if constexpr (MODE == 0) {
          q0 = *(const float4*)(qb + kk * 256);
          q1 = *(const float4*)(qb + kk * 256 + 4);
        } else {
          q0 = *(const float4*)(&s2b[kk * 256] + so0);
          q1 = *(const float4*)(&s2b[kk * 256] + so1);
        }
        const float ar[2] = {a.x, a.y};
        const float wm[8] = {w0.x, w0.y, w0.z, w0.w, w1.x, w1.y, w1.z, w1.w};
        const float wsq[8] = {q0.x, q0.y, q0.z, q0.w, q1.x, q1.y, q1.z, q1.w};
        #pragma unroll
        for (int rr = 0; rr < 2; ++rr) {
          const float hv = ar[rr];
          const float h2 = __fmul_rn(hv, hv);
          #pragma unroll
          for (int c = 0; c < 8; ++c) {
            am[rr][c] = fmaf(hv, wm[c], am[rr][c]);
            av[rr][c] = fmaf(h2, wsq[c], av[rr][c]);
          }
        }
      }
    }

    {
      const float* mub_p = mu + 256 * 256;
      #pragma unroll
      for (int c = 0; c < 8; ++c) {
        const int col = tc * 8 + c;
        const float mub = mub_p[col];
        float vb;
        if constexpr (MODE == 0) {
          vb = qw[256 * 256 + col];
        } else {
          const float spb = softplus_ref(ls[(size_t)256 * 256 + col]);
          vb = __fmul_rn(spb, spb);
        }
        #pragma unroll
        for (int rr = 0; rr < 2; ++rr) {
          float m   = __fadd_rn(am[rr][c], mub);
          float var = __fadd_rn(__fadd_rn(av[rr][c], vb), 1e-14f);
          float sv  = __fsqrt_rn(var);
          uint32_t idx = ((uint32_t)(s * NPTS + n0 + rowA + rr)) * 256u + (uint32_t)col;
          float nz = jax_normal32(lk0, lk1, idx);
          float z  = __fadd_rn(m, __fmul_rn(sv, nz));
          am[rr][c] = sinf(__fmul_rn(30.0f, z));
        }
      }
    }
    __syncthreads();
    {
      const int wrow = rowA ^ ((tc & 7) << 1);
      #pragma unroll
      for (int c = 0; c < 8; ++c) {
        *(float2*)&hTf[((tc * 8 + c) << 4) + wrow] = make_float2(am[0][c], am[1][c]);
      }
    }
    __syncthreads();
  }

  {
    const float* __restrict__ mu = mu4 + (size_t)s * (257 * 3);
    const float* __restrict__ ls = ls4 + (size_t)s * (257 * 3);
    const float* __restrict__ q4 =
        (MODE == 0) ? (ws + FB_WS_L4 + (size_t)s * 771) : nullptr;
    float* s2w = nullptr;
    if constexpr (MODE == 1) {
      s2w = &s2b[0];
      for (int e = tid; e < 771; e += 256) {
        float sp = softplus_ref(ls[e]);
        s2w[e] = __fmul_rn(sp, sp);
      }
      __syncthreads();
    }

    const int r = tid >> 4, o = tid & 15;
    if (o < 3) {
      float am = 0.f, av2 = 0.f;
      #pragma unroll 4
      for (int k = 0; k < 256; ++k) {
        float hv = hTf[HT_IDX(k, r)];
        float sq = (MODE == 0) ? q4[k * 3 + o] : s2w[k * 3 + o];
        am  = fmaf(hv, mu[k * 3 + o], am);
        av2 = fmaf(__fmul_rn(hv, hv), sq, av2);
      }
      float bsq = (MODE == 0) ? q4[256 * 3 + o] : s2w[256 * 3 + o];
      float m   = __fadd_rn(am, mu[256 * 3 + o]);
      float var = __fadd_rn(__fadd_rn(av2, bsq), 1e-14f);
      float sv  = __fsqrt_rn(var);
      const int n = n0 + r;
      uint32_t idx = ((uint32_t)(s * NPTS + n)) * 3u + (uint32_t)o;
      float nz = jax_normal32(keys.k0[4], keys.k1[4], idx);
      out[(size_t)(s * NPTS + n) * 3 + o] = __fadd_rn(m, __fmul_rn(sv, nz));
    }
  }
}

extern "C" void kernel_launch(void* const* d_in, const int* in_sizes, int n_in,
                              void* d_out, int out_size, void* d_ws, size_t ws_size,
                              hipStream_t stream) {
  (void)in_sizes; (void)n_in; (void)out_size;
  const float* X   = (const float*)d_in[0];
  const float* mu0 = (const float*)d_in[1];
  const float* ls0 = (const float*)d_in[2];
  const float* mu1 = (const float*)d_in[3];
  const float* ls1 = (const float*)d_in[4];
  const float* mu2 = (const float*)d_in[5];
  const float* ls2 = (const float*)d_in[6];
  const float* mu3 = (const float*)d_in[7];
  const float* ls3 = (const float*)d_in[8];
  const float* mu4 = (const float*)d_in[9];
  const float* ls4 = (const float*)d_in[10];

  Keys keys;
  for (int l = 0; l < 5; ++l) {
    uint32_t o0, o1;
    threefry2x32(0u, 42u, 0u, (uint32_t)l, o0, o1);
    keys.k0[l] = o0; keys.k1[l] = o1;
  }

  if (d_ws != nullptr && ws_size >= WS_NEED) {
    ushort_t* wsu = (ushort_t*)d_ws;
    float* wsf = (float*)((char*)d_ws + WSF_BYTE_OFF);
    prep_tsplit<<<dim3(4096), dim3(256), 0, stream>>>(
        mu0, mu1, mu2, mu3, ls0, ls1, ls2, ls3, wsu);
    prep_bias<<<dim3(320), dim3(256), 0, stream>>>(ls0, ls1, ls2, ls3, ls4, wsf);
    vsiren_mfma<<<dim3(16384), dim3(512), 0, stream>>>(
        X, mu0, mu1, mu2, mu3, mu4, wsu, wsf, (float*)d_out, keys);
  } else if (d_ws != nullptr && ws_size >= FB_WS_BYTES) {
    float* ws = (float*)d_ws;
    const float* lsp[4] = {ls0, ls1, ls2, ls3};
    for (int l = 0; l < 4; ++l)
      softplus2_kernel<<<dim3(2048), dim3(256), 0, stream>>>(
          lsp[l], ws + (size_t)l * FB_WS_L, FB_WS_L / 4);
    softplus2_kernel<<<dim3(64), dim3(256), 0, stream>>>(
        ls4, ws + FB_WS_L4, (FB_WS_TOT - FB_WS_L4) / 4);
    vsiren_fb<0><<<dim3(FB_NBLOCKS), dim3(256), 0, stream>>>(
        X, mu0, ls0, mu1, ls1, mu2, ls2, mu3, ls3, mu4, ls4,
        ws, (float*)d_out, keys);
  } else {
    vsiren_fb<1><<<dim3(FB_NBLOCKS), dim3(256), 0, stream>>>(
        X, mu0, ls0, mu1, ls1, mu2, ls2, mu3, ls3, mu4, ls4,
        nullptr, (float*)d_out, keys);
  }
}

// Round 6
// 7832.220 us; speedup vs baseline: 5.8259x; 1.0206x over previous
//
#include <hip/hip_runtime.h>
#include <hip/hip_bf16.h>
#include <stdint.h>

#define NSIZE   64
#define NPTS    8192

struct Keys { uint32_t k0[5]; uint32_t k1[5]; };

typedef unsigned short ushort_t;
typedef __attribute__((ext_vector_type(8))) short bh8;
typedef __attribute__((ext_vector_type(4))) float f32x4;

// ---------------- threefry2x32, 20 rounds (JAX-compatible) ----------------
#define TF_ROUNDS_A(x0,x1) \
  x0 += x1; x1 = (x1<<13)|(x1>>19); x1 ^= x0; \
  x0 += x1; x1 = (x1<<15)|(x1>>17); x1 ^= x0; \
  x0 += x1; x1 = (x1<<26)|(x1>>6);  x1 ^= x0; \
  x0 += x1; x1 = (x1<<6) |(x1>>26); x1 ^= x0;
#define TF_ROUNDS_B(x0,x1) \
  x0 += x1; x1 = (x1<<17)|(x1>>15); x1 ^= x0; \
  x0 += x1; x1 = (x1<<29)|(x1>>3);  x1 ^= x0; \
  x0 += x1; x1 = (x1<<16)|(x1>>16); x1 ^= x0; \
  x0 += x1; x1 = (x1<<24)|(x1>>8);  x1 ^= x0;

__host__ __device__ inline void threefry2x32(uint32_t k0, uint32_t k1,
                                             uint32_t c0, uint32_t c1,
                                             uint32_t& o0, uint32_t& o1) {
  uint32_t k2 = k0 ^ k1 ^ 0x1BD11BDAu;
  uint32_t x0 = c0 + k0, x1 = c1 + k1;
  TF_ROUNDS_A(x0,x1) x0 += k1; x1 += k2 + 1u;
  TF_ROUNDS_B(x0,x1) x0 += k2; x1 += k0 + 2u;
  TF_ROUNDS_A(x0,x1) x0 += k0; x1 += k1 + 3u;
  TF_ROUNDS_B(x0,x1) x0 += k1; x1 += k2 + 4u;
  TF_ROUNDS_A(x0,x1) x0 += k2; x1 += k0 + 5u;
  o0 = x0; o1 = x1;
}

__device__ __forceinline__ float jax_normal32(uint32_t k0, uint32_t k1, uint32_t idx) {
  uint32_t o0, o1;
  threefry2x32(k0, k1, 0u, idx, o0, o1);
  uint32_t bits = o0 ^ o1;
  float u01 = __uint_as_float((bits >> 9) | 0x3f800000u) - 1.0f;
  float u = __fadd_rn(__fmul_rn(u01, 2.0f), -0.99999994f);
  u = fmaxf(u, -0.99999994f);
  float xx = __fmul_rn(u, u);
  float w = -log1pf(-xx);
  float p;
  if (w < 5.0f) {
    w = __fadd_rn(w, -2.5f);
    p =                2.81022636e-08f;
    p = __fadd_rn( 3.43273939e-07f, __fmul_rn(p, w));
    p = __fadd_rn(-3.5233877e-06f,  __fmul_rn(p, w));
    p = __fadd_rn(-4.39150654e-06f, __fmul_rn(p, w));
    p = __fadd_rn( 0.00021858087f,  __fmul_rn(p, w));
    p = __fadd_rn(-0.00125372503f,  __fmul_rn(p, w));
    p = __fadd_rn(-0.00417768164f,  __fmul_rn(p, w));
    p = __fadd_rn( 0.246640727f,    __fmul_rn(p, w));
    p = __fadd_rn( 1.50140941f,     __fmul_rn(p, w));
  } else {
    w = __fadd_rn(__fsqrt_rn(w), -3.0f);
    p =               -0.000200214257f;
    p = __fadd_rn( 0.000100950558f, __fmul_rn(p, w));
    p = __fadd_rn( 0.00134934322f,  __fmul_rn(p, w));
    p = __fadd_rn(-0.00367342844f,  __fmul_rn(p, w));
    p = __fadd_rn( 0.00573950773f,  __fmul_rn(p, w));
    p = __fadd_rn(-0.0076224613f,   __fmul_rn(p, w));
    p = __fadd_rn( 0.00943887047f,  __fmul_rn(p, w));
    p = __fadd_rn( 1.00167406f,     __fmul_rn(p, w));
    p = __fadd_rn( 2.83297682f,     __fmul_rn(p, w));
  }
  return __fmul_rn(1.41421356f, __fmul_rn(p, u));
}

__device__ __forceinline__ float softplus_ref(float x) {
  float l = log1pf(expf(fminf(x, 20.0f)));
  return (x > 20.0f) ? x : l;
}

// ================= MFMA path =================
// ws layout (ushort idx): MH 0 | ML 16777216 | QH 33554432 | QL 50331648
// then f32 region at byte 134217728: q2_b[4*64*256], q4[64*771]
#define U_MH 0u
#define U_ML 16777216u
#define U_QH 33554432u
#define WSF_BYTE_OFF 134217728u
#define WS_NEED (134217728ull + (65536ull + 49344ull) * 4ull)

// transpose+split weights: bid = ((arr*4 + l)*64 + s)*8 + kc   (grid 4096)
__global__ __launch_bounds__(256)
void prep_tsplit(const float* __restrict__ mu0, const float* __restrict__ mu1,
                 const float* __restrict__ mu2, const float* __restrict__ mu3,
                 const float* __restrict__ ls0, const float* __restrict__ ls1,
                 const float* __restrict__ ls2, const float* __restrict__ ls3,
                 ushort_t* __restrict__ wsu)
{
  const int bid = blockIdx.x;
  const int kc = bid & 7, s = (bid >> 3) & 63, l = (bid >> 9) & 3, arr = bid >> 11;
  const float* src =
      (l == 0) ? (arr ? ls0 : mu0) : (l == 1) ? (arr ? ls1 : mu1)
    : (l == 2) ? (arr ? ls2 : mu2) : (arr ? ls3 : mu3);
  src += (size_t)s * 65792 + (size_t)kc * 32 * 256;
  ushort_t* dhi = wsu + (arr ? U_QH : U_MH) + (size_t)(l * 64 + s) * 65536 + kc * 32;
  ushort_t* dlo = dhi + U_ML;   // lo region is +16777216 for both mu and q2

  __shared__ float tile[32][260];
  const int t = threadIdx.x;
  #pragma unroll 8
  for (int rr = 0; rr < 32; ++rr) tile[rr][t] = src[rr * 256 + t];
  __syncthreads();

  __align__(16) ushort_t hib[32], lob[32];
  #pragma unroll 8
  for (int kk = 0; kk < 32; ++kk) {
    float v = tile[kk][t];
    if (arr) { float sp = softplus_ref(v); v = __fmul_rn(sp, sp); }
    __hip_bfloat16 hb = __float2bfloat16(v);
    float hf = __bfloat162float(hb);
    __hip_bfloat16 lb = __float2bfloat16(__fsub_rn(v, hf));
    hib[kk] = *(ushort_t*)&hb;
    lob[kk] = *(ushort_t*)&lb;
  }
  ushort_t* ph = dhi + (size_t)t * 256;
  ushort_t* pl = dlo + (size_t)t * 256;
  #pragma unroll
  for (int i = 0; i < 4; ++i) {
    *(uint4*)(ph + i * 8) = *(const uint4*)(hib + i * 8);
    *(uint4*)(pl + i * 8) = *(const uint4*)(lob + i * 8);
  }
}

// biases: bid<256 -> q2_b for (l,s); bid 256..319 -> layer4 q4   (grid 320)
__global__ __launch_bounds__(256)
void prep_bias(const float* __restrict__ ls0, const float* __restrict__ ls1,
               const float* __restrict__ ls2, const float* __restrict__ ls3,
               const float* __restrict__ ls4, float* __restrict__ wsf)
{
  const int bid = blockIdx.x, t = threadIdx.x;
  if (bid < 256) {
    const int l = bid >> 6, s = bid & 63;
    const float* ls = ((l == 0) ? ls0 : (l == 1) ? ls1 : (l == 2) ? ls2 : ls3)
                      + (size_t)s * 65792 + 65536;
    float sp = softplus_ref(ls[t]);
    wsf[(size_t)(l * 64 + s) * 256 + t] = __fmul_rn(sp, sp);
  } else {
    const int s = bid - 256;
    for (int e = t; e < 771; e += 256) {
      float sp = softplus_ref(ls4[(size_t)s * 771 + e]);
      wsf[65536 + (size_t)s * 771 + e] = __fmul_rn(sp, sp);
    }
  }
}

// main MFMA kernel: 512 thr (8 waves), 32 rows/block.
// launch_bounds: single-arg ONLY. Empirical toolchain law (r1-r5): second arg N
// acts as MAX waves/EU = N and VGPR cap = 256/N; (512,2) pinned us to 1
// block/CU (24% occupancy). Single-arg leaves the scheduler free (2-3 blocks).
__global__ __launch_bounds__(512)
void vsiren_mfma(const float* __restrict__ X,
                 const float* __restrict__ mu0, const float* __restrict__ mu1,
                 const float* __restrict__ mu2, const float* __restrict__ mu3,
                 const float* __restrict__ mu4,
                 const ushort_t* __restrict__ wsu, const float* __restrict__ wsf,
                 float* __restrict__ out, Keys keys)
{
  __shared__ ushort_t hhi[8192], hlo[8192], hsq[8192];   // 3 x 16 KB, XOR-swizzled
  const int tid = threadIdx.x;
  const int w = tid >> 6, lane = tid & 63, lr = lane & 15, g = lane >> 4;
  const uint32_t bid = blockIdx.x;
  const uint32_t swz = (bid & 7u) * 2048u + (bid >> 3);   // XCD swizzle
  const int s  = (int)(swz >> 8);
  const int n0 = (int)(swz & 255u) * 32;

  // ---- posenc -> LDS (hi, lo, sq) ----
  {
    const int r = tid & 31, p = tid >> 5;
    const float x0 = X[(size_t)(s * NPTS + n0 + r) * 2 + 0];
    const float x1 = X[(size_t)(s * NPTS + n0 + r) * 2 + 1];
    const float delta = 6.93147182464599609375f / 63.0f;
    const int xsh = (r & 7) << 3;
    #pragma unroll 4
    for (int jj = 0; jj < 16; ++jj) {
      const int f = p * 16 + jj;
      const int trg = f >> 7, d = (f >> 6) & 1, kf = f & 63;
      const float xv = d ? x1 : x0;
      float wf = expf(__fmul_rn((float)kf, delta));
      float arg = __fmul_rn(3.14159274101257324f, __fmul_rn(xv, wf));
      float v = trg ? sinf(arg) : cosf(arg);
      __hip_bfloat16 hb = __float2bfloat16(v);
      float hf = __bfloat162float(hb);
      __hip_bfloat16 lb = __float2bfloat16(__fsub_rn(v, hf));
      __hip_bfloat16 qv = __float2bfloat16(__fmul_rn(v, v));
      const int wi = r * 256 + (f ^ xsh);
      hhi[wi] = *(ushort_t*)&hb; hlo[wi] = *(ushort_t*)&lb; hsq[wi] = *(ushort_t*)&qv;
    }
  }
  __syncthreads();

  const int c0 = w * 32 + lr;

  #pragma unroll 1
  for (int l = 0; l < 4; ++l) {
    const size_t wb = (size_t)(l * 64 + s) * 65536;
    const ushort_t* mh = wsu + U_MH + wb;
    const ushort_t* ml = wsu + U_ML + wb;
    const ushort_t* qh = wsu + U_QH + wb;
    const ushort_t* ql = wsu + U_QH + U_ML + wb;
    const float* mubp = ((l == 0) ? mu0 : (l == 1) ? mu1 : (l == 2) ? mu2 : mu3)
                        + (size_t)s * 65792 + 65536;
    const float* qbp = wsf + (size_t)(l * 64 + s) * 256;
    const uint32_t lk0 = (l == 0) ? keys.k0[0] : (l == 1) ? keys.k0[1] : (l == 2) ? keys.k0[2] : keys.k0[3];
    const uint32_t lk1 = (l == 0) ? keys.k1[0] : (l == 1) ? keys.k1[1] : (l == 2) ? keys.k1[2] : keys.k1[3];

    // SWAPPED operands: am[ct][b] = W^T-tile x H-tile  (transposed output).
    // Lane owns point-row rl=b*16+lr, cols cb..cb+3 with cb=w*32+ct*16+g*4.
    f32x4 am[2][2], av[2][2];
    #pragma unroll
    for (int a = 0; a < 2; ++a)
      #pragma unroll
      for (int b = 0; b < 2; ++b) {
        am[a][b] = (f32x4){0.f, 0.f, 0.f, 0.f};
        av[a][b] = (f32x4){0.f, 0.f, 0.f, 0.f};
      }

    #pragma unroll 2
    for (int ks = 0; ks < 8; ++ks) {
      bh8 Ahi[2], Alo[2], Asq[2];
      #pragma unroll
      for (int b = 0; b < 2; ++b) {
        const int rl = b * 16 + lr;
        const int ri = rl * 256 + ((ks * 32 + g * 8) ^ ((rl & 7) << 3));
        Ahi[b] = *(const bh8*)&hhi[ri];
        Alo[b] = *(const bh8*)&hlo[ri];
        Asq[b] = *(const bh8*)&hsq[ri];
      }
      #pragma unroll
      for (int ct = 0; ct < 2; ++ct) {
        const size_t eo = (size_t)(c0 + ct * 16) * 256 + (size_t)(ks * 32 + g * 8);
        const bh8 WH = *(const bh8*)&mh[eo];
        const bh8 WL = *(const bh8*)&ml[eo];
        const bh8 QH = *(const bh8*)&qh[eo];
        const bh8 QL = *(const bh8*)&ql[eo];
        #pragma unroll
        for (int b = 0; b < 2; ++b) {
          am[ct][b] = __builtin_amdgcn_mfma_f32_16x16x32_bf16(WH, Ahi[b], am[ct][b], 0, 0, 0);
          am[ct][b] = __builtin_amdgcn_mfma_f32_16x16x32_bf16(WH, Alo[b], am[ct][b], 0, 0, 0);
          am[ct][b] = __builtin_amdgcn_mfma_f32_16x16x32_bf16(WL, Ahi[b], am[ct][b], 0, 0, 0);
          av[ct][b] = __builtin_amdgcn_mfma_f32_16x16x32_bf16(QH, Asq[b], av[ct][b], 0, 0, 0);
          av[ct][b] = __builtin_amdgcn_mfma_f32_16x16x32_bf16(QL, Asq[b], av[ct][b], 0, 0, 0);
        }
      }
    }
    __syncthreads();   // all LDS A-reads for this layer done

    // ---- epilogue: bias, variance, noise, sin -> coalesced b64 LDS writes ----
    #pragma unroll
    for (int ct = 0; ct < 2; ++ct) {
      const int cb = w * 32 + ct * 16 + g * 4;
      const float4 mub4 = *(const float4*)&mubp[cb];
      const float4 qb4  = *(const float4*)&qbp[cb];
      const float mubA[4] = {mub4.x, mub4.y, mub4.z, mub4.w};
      const float qbA[4]  = {qb4.x, qb4.y, qb4.z, qb4.w};
      #pragma unroll
      for (int b = 0; b < 2; ++b) {
        const int rl = b * 16 + lr;
        const uint32_t idx0 = ((uint32_t)(s * NPTS + n0 + rl)) * 256u + (uint32_t)cb;
        __align__(8) ushort_t hb4[4], lb4[4], sq4[4];
        #pragma unroll
        for (int j = 0; j < 4; ++j) {
          float m   = __fadd_rn(am[ct][b][j], mubA[j]);
          float var = __fadd_rn(__fadd_rn(av[ct][b][j], qbA[j]), 1e-14f);
          float sv  = __fsqrt_rn(var);
          float nz = jax_normal32(lk0, lk1, idx0 + (uint32_t)j);
          float z  = __fadd_rn(m, __fmul_rn(sv, nz));
          float a  = sinf(__fmul_rn(30.0f, z));
          __hip_bfloat16 hb = __float2bfloat16(a);
          float hf = __bfloat162float(hb);
          __hip_bfloat16 lb = __float2bfloat16(__fsub_rn(a, hf));
          __hip_bfloat16 sq = __float2bfloat16(__fmul_rn(a, a));
          hb4[j] = *(ushort_t*)&hb; lb4[j] = *(ushort_t*)&lb; sq4[j] = *(ushort_t*)&sq;
        }
        const int wi = rl * 256 + (cb ^ ((rl & 7) << 3));
        *(uint2*)&hhi[wi] = *(const uint2*)hb4;
        *(uint2*)&hlo[wi] = *(const uint2*)lb4;
        *(uint2*)&hsq[wi] = *(const uint2*)sq4;
      }
    }
    __syncthreads();
  } // layer

  // ---- layer 4: 256 -> 3 (no sin), k split 4-way + shfl reduce ----
  {
    const int r = tid >> 4, o = tid & 3, q = (tid >> 2) & 3;
    const float* m4 = mu4 + (size_t)s * 771;
    const float* q4 = wsf + 65536 + (size_t)s * 771;
    const int oo = (o < 3) ? o : 0;
    const int xsh = (r & 7) << 3;
    float am4 = 0.f, av4 = 0.f;
    #pragma unroll 4
    for (int kk = 0; kk < 64; ++kk) {
      const int k = q * 64 + kk;
      const int ri = r * 256 + (k ^ xsh);
      float hv = __fadd_rn(__bfloat162float(*(const __hip_bfloat16*)&hhi[ri]),
                           __bfloat162float(*(const __hip_bfloat16*)&hlo[ri]));
      am4 = fmaf(hv, m4[k * 3 + oo], am4);
      av4 = fmaf(__fmul_rn(hv, hv), q4[k * 3 + oo], av4);
    }
    am4 = __fadd_rn(am4, __shfl_xor(am4, 4));
    am4 = __fadd_rn(am4, __shfl_xor(am4, 8));
    av4 = __fadd_rn(av4, __shfl_xor(av4, 4));
    av4 = __fadd_rn(av4, __shfl_xor(av4, 8));
    if (o < 3 && q == 0) {
      float m   = __fadd_rn(am4, m4[768 + o]);
      float var = __fadd_rn(__fadd_rn(av4, q4[768 + o]), 1e-14f);
      float sv  = __fsqrt_rn(var);
      const int n = n0 + r;
      uint32_t idx = ((uint32_t)(s * NPTS + n)) * 3u + (uint32_t)o;
      float nz = jax_normal32(keys.k0[4], keys.k1[4], idx);
      out[(size_t)(s * NPTS + n) * 3 + o] = __fadd_rn(m, __fmul_rn(sv, nz));
    }
  }
}

// ================= fallback (round-4) path =================
#define FB_NTILE 16
#define FB_NBLOCKS (NSIZE * (NPTS / FB_NTILE))
#define FB_WS_L    4210688
#define FB_WS_L4   16842752
#define FB_WS_TOT  16892096
#define FB_WS_BYTES ((size_t)FB_WS_TOT * 4)

__global__ void softplus2_kernel(const float* __restrict__ src,
                                 float* __restrict__ dst, int n4) {
  int i = blockIdx.x * blockDim.x + threadIdx.x;
  const int stride = gridDim.x * blockDim.x;
  for (; i < n4; i += stride) {
    float4 v = ((const float4*)src)[i];
    float a = softplus_ref(v.x), b = softplus_ref(v.y);
    float c = softplus_ref(v.z), d = softplus_ref(v.w);
    ((float4*)dst)[i] = make_float4(__fmul_rn(a, a), __fmul_rn(b, b),
                                    __fmul_rn(c, c), __fmul_rn(d, d));
  }
}

#define HT_IDX(col, row) (((col) << 4) + ((row) ^ ((((col) >> 3) & 7) << 1)))

template<int MODE>
__global__ __launch_bounds__(256)
void vsiren_fb(const float* __restrict__ X,
               const float* __restrict__ mu0, const float* __restrict__ ls0,
               const float* __restrict__ mu1, const float* __restrict__ ls1,
               const float* __restrict__ mu2, const float* __restrict__ ls2,
               const float* __restrict__ mu3, const float* __restrict__ ls3,
               const float* __restrict__ mu4, const float* __restrict__ ls4,
               const float* __restrict__ ws,
               float* __restrict__ out, Keys keys)
{
  __shared__ float hTf[256 * FB_NTILE];
  __shared__ float s2b[(MODE == 1) ? 8 * 256 : 4];

  const int tid = threadIdx.x;
  const uint32_t bid = blockIdx.x;
  const uint32_t swz = (bid & 7u) * (FB_NBLOCKS / 8) + (bid >> 3);
  const int s  = (int)(swz >> 9);
  const int n0 = (int)(swz & 511u) * FB_NTILE;

  {
    const int r = tid & 15, p = tid >> 4;
    const int d = p & 1, trg = (p >> 1) & 1, kh = p >> 2;
    const float xv = X[(size_t)(s * NPTS + n0 + r) * 2 + d];
    const float delta = 6.93147182464599609375f / 63.0f;
    #pragma unroll 4
    for (int j = 0; j < 16; ++j) {
      const int kf = kh * 16 + j;
      const int f = trg * 128 + d * 64 + kf;
      float w = expf(__fmul_rn((float)kf, delta));
      float arg = __fmul_rn(3.14159274101257324f, __fmul_rn(xv, w));
      hTf[HT_IDX(f, r)] = trg ? sinf(arg) : cosf(arg);
    }
  }
  __syncthreads();

  const int tc = tid & 31;
  const int tr = tid >> 5;
  const int rowA = tr * 2;
  const int c0 = 2 * tc, c1 = 2 * tc + 1;
  const int so0 = (c0 ^ ((c0 >> 3) & 7)) * 4;
  const int so1 = (c1 ^ ((c1 >> 3) & 7)) * 4;

  #pragma unroll 1
  for (int l = 0; l < 4; ++l) {
    const float* __restrict__ mu =
        ((l == 0) ? mu0 : (l == 1) ? mu1 : (l == 2) ? mu2 : mu3) + (size_t)s * (257 * 256);
    const float* __restrict__ ls =
        ((l == 0) ? ls0 : (l == 1) ? ls1 : (l == 2) ? ls2 : ls3) + (size_t)s * (257 * 256);
    const float* __restrict__ qw =
        (MODE == 0) ? (ws + (size_t)l * FB_WS_L + (size_t)s * (257 * 256)) : nullptr;
    const uint32_t lk0 = (l == 0) ? keys.k0[0] : (l == 1) ? keys.k0[1] : (l == 2) ? keys.k0[2] : keys.k0[3];
    const uint32_t lk1 = (l == 0) ? keys.k1[0] : (l == 1) ? keys.k1[1] : (l == 2) ? keys.k1[2] : keys.k1[3];

    float am[2][8], av[2][8];
    #pragma unroll
    for (int i = 0; i < 2; ++i)
      #pragma unroll
      for (int j = 0; j < 8; ++j) { am[i][j] = 0.f; av[i][j] = 0.f; }

    #pragma unroll 1
    for (int ch = 0; ch < 32; ++ch) {
      if constexpr (MODE == 1) {
        __syncthreads();
        const float* lsrow = ls + (size_t)(ch * 8 + (tid >> 5)) * 256 + tc * 8;
        const float4 l0v = *(const float4*)lsrow;
        const float4 l1v = *(const float4*)(lsrow + 4);
        float a0 = softplus_ref(l0v.x), a1 = softplus_ref(l0v.y);
        float a2 = softplus_ref(l0v.z), a3 = softplus_ref(l0v.w);
        float b0 = softplus_ref(l1v.x), b1 = softplus_ref(l1v.y);
        float b2 = softplus_ref(l1v.z), b3 = softplus_ref(l1v.w);
        float* dst = &s2b[(tid >> 5) * 256];
        *(float4*)(dst + so0) = make_float4(__fmul_rn(a0, a0), __fmul_rn(a1, a1),
                                            __fmul_rn(a2, a2), __fmul_rn(a3, a3));
        *(float4*)(dst + so1) = make_float4(__fmul_rn(b0, b0), __fmul_rn(b1, b1),
                                            __fmul_rn(b2, b2), __fmul_rn(b3, b3));
        __syncthreads();
      }

      const float* ab = &hTf[(ch * 8) * 16 + (rowA ^ ((ch & 7) << 1))];
      const float* wb = mu + (size_t)(ch * 8) * 256 + tc * 8;
      const float* qb = (MODE == 0) ? (qw + (size_t)(ch * 8) * 256 + tc * 8) : nullptr;

      #pragma unroll
      for (int kk = 0; kk < 8; ++kk) {
        const float2 a  = *(const float2*)(ab + kk * 16);
        const float4 w0 = *(const float4*)(wb + kk * 256);
        const float4 w1 = *(const float4*)(wb + kk * 256 + 4);
        float4 q0, q1;
        if constexpr (MODE == 0) {
          q0 = *(const float4*)(qb + kk * 256);
          q1 = *(const float4*)(qb + kk * 256 + 4);
        } else {
          q0 = *(const float4*)(&s2b[kk * 256] + so0);
          q1 = *(const float4*)(&s2b[kk * 256] + so1);
        }
        const float ar[2] = {a.x, a.y};
        const float wm[8] = {w0.x, w0.y, w0.z, w0.w, w1.x, w1.y, w1.z, w1.w};
        const float wsq[8] = {q0.x, q0.y, q0.z, q0.w, q1.x, q1.y, q1.z, q1.w};
        #pragma unroll
        for (int rr = 0; rr < 2; ++rr) {
          const float hv = ar[rr];
          const float h2 = __fmul_rn(hv, hv);
          #pragma unroll
          for (int c = 0; c < 8; ++c) {
            am[rr][c] = fmaf(hv, wm[c], am[rr][c]);
            av[rr][c] = fmaf(h2, wsq[c], av[rr][c]);
          }
        }
      }
    }

    {
      const float* mub_p = mu + 256 * 256;
      #pragma unroll
      for (int c = 0; c < 8; ++c) {
        const int col = tc * 8 + c;
        const float mub = mub_p[col];
        float vb;
        if constexpr (MODE == 0) {
          vb = qw[256 * 256 + col];
        } else {
          const float spb = softplus_ref(ls[(size_t)256 * 256 + col]);
          vb = __fmul_rn(spb, spb);
        }
        #pragma unroll
        for (int rr = 0; rr < 2; ++rr) {
          float m   = __fadd_rn(am[rr][c], mub);
          float var = __fadd_rn(__fadd_rn(av[rr][c], vb), 1e-14f);
          float sv  = __fsqrt_rn(var);
          uint32_t idx = ((uint32_t)(s * NPTS + n0 + rowA + rr)) * 256u + (uint32_t)col;
          float nz = jax_normal32(lk0, lk1, idx);
          float z  = __fadd_rn(m, __fmul_rn(sv, nz));
          am[rr][c] = sinf(__fmul_rn(30.0f, z));
        }
      }
    }
    __syncthreads();
    {
      const int wrow = rowA ^ ((tc & 7) << 1);
      #pragma unroll
      for (int c = 0; c < 8; ++c) {
        *(float2*)&hTf[((tc * 8 + c) << 4) + wrow] = make_float2(am[0][c], am[1][c]);
      }
    }
    __syncthreads();
  }

  {
    const float* __restrict__ mu = mu4 + (size_t)s * (257 * 3);
    const float* __restrict__ ls = ls4 + (size_t)s * (257 * 3);
    const float* __restrict__ q4 =
        (MODE == 0) ? (ws + FB_WS_L4 + (size_t)s * 771) : nullptr;
    float* s2w = nullptr;
    if constexpr (MODE == 1) {
      s2w = &s2b[0];
      for (int e = tid; e < 771; e += 256) {
        float sp = softplus_ref(ls[e]);
        s2w[e] = __fmul_rn(sp, sp);
      }
      __syncthreads();
    }

    const int r = tid >> 4, o = tid & 15;
    if (o < 3) {
      float am = 0.f, av2 = 0.f;
      #pragma unroll 4
      for (int k = 0; k < 256; ++k) {
        float hv = hTf[HT_IDX(k, r)];
        float sq = (MODE == 0) ? q4[k * 3 + o] : s2w[k * 3 + o];
        am  = fmaf(hv, mu[k * 3 + o], am);
        av2 = fmaf(__fmul_rn(hv, hv), sq, av2);
      }
      float bsq = (MODE == 0) ? q4[256 * 3 + o] : s2w[256 * 3 + o];
      float m   = __fadd_rn(am, mu[256 * 3 + o]);
      float var = __fadd_rn(__fadd_rn(av2, bsq), 1e-14f);
      float sv  = __fsqrt_rn(var);
      const int n = n0 + r;
      uint32_t idx = ((uint32_t)(s * NPTS + n)) * 3u + (uint32_t)o;
      float nz = jax_normal32(keys.k0[4], keys.k1[4], idx);
      out[(size_t)(s * NPTS + n) * 3 + o] = __fadd_rn(m, __fmul_rn(sv, nz));
    }
  }
}

extern "C" void kernel_launch(void* const* d_in, const int* in_sizes, int n_in,
                              void* d_out, int out_size, void* d_ws, size_t ws_size,
                              hipStream_t stream) {
  (void)in_sizes; (void)n_in; (void)out_size;
  const float* X   = (const float*)d_in[0];
  const float* mu0 = (const float*)d_in[1];
  const float* ls0 = (const float*)d_in[2];
  const float* mu1 = (const float*)d_in[3];
  const float* ls1 = (const float*)d_in[4];
  const float* mu2 = (const float*)d_in[5];
  const float* ls2 = (const float*)d_in[6];
  const float* mu3 = (const float*)d_in[7];
  const float* ls3 = (const float*)d_in[8];
  const float* mu4 = (const float*)d_in[9];
  const float* ls4 = (const float*)d_in[10];

  Keys keys;
  for (int l = 0; l < 5; ++l) {
    uint32_t o0, o1;
    threefry2x32(0u, 42u, 0u, (uint32_t)l, o0, o1);
    keys.k0[l] = o0; keys.k1[l] = o1;
  }

  if (d_ws != nullptr && ws_size >= WS_NEED) {
    ushort_t* wsu = (ushort_t*)d_ws;
    float* wsf = (float*)((char*)d_ws + WSF_BYTE_OFF);
    prep_tsplit<<<dim3(4096), dim3(256), 0, stream>>>(
        mu0, mu1, mu2, mu3, ls0, ls1, ls2, ls3, wsu);
    prep_bias<<<dim3(320), dim3(256), 0, stream>>>(ls0, ls1, ls2, ls3, ls4, wsf);
    vsiren_mfma<<<dim3(16384), dim3(512), 0, stream>>>(
        X, mu0, mu1, mu2, mu3, mu4, wsu, wsf, (float*)d_out, keys);
  } else if (d_ws != nullptr && ws_size >= FB_WS_BYTES) {
    float* ws = (float*)d_ws;
    const float* lsp[4] = {ls0, ls1, ls2, ls3};
    for (int l = 0; l < 4; ++l)
      softplus2_kernel<<<dim3(2048), dim3(256), 0, stream>>>(
          lsp[l], ws + (size_t)l * FB_WS_L, FB_WS_L / 4);
    softplus2_kernel<<<dim3(64), dim3(256), 0, stream>>>(
        ls4, ws + FB_WS_L4, (FB_WS_TOT - FB_WS_L4) / 4);
    vsiren_fb<0><<<dim3(FB_NBLOCKS), dim3(256), 0, stream>>>(
        X, mu0, ls0, mu1, ls1, mu2, ls2, mu3, ls3, mu4, ls4,
        ws, (float*)d_out, keys);
  } else {
    vsiren_fb<1><<<dim3(FB_NBLOCKS), dim3(256), 0, stream>>>(
        X, mu0, ls0, mu1, ls1, mu2, ls2, mu3, ls3, mu4, ls4,
        nullptr, (float*)d_out, keys);
  }
}